// Round 2
// baseline (842.909 us; speedup 1.0000x reference)
//
#include <hip/hip_runtime.h>
#include <hip/hip_bf16.h>
#include <cstdint>

// Problem constants (fixed by reference)
#define NN 100000
#define HH 96
#define AD 32
#define DE 16
#define EE 500000
#define NEG 0.01f

typedef __bf16 bf16x8 __attribute__((ext_vector_type(8)));
typedef float  f32x4  __attribute__((ext_vector_type(4)));

__device__ __forceinline__ unsigned short f2b(float x) {
    union { float f; unsigned int u; } v; v.f = x;
    unsigned int r = v.u + 0x7fffu + ((v.u >> 16) & 1u);  // RNE
    return (unsigned short)(r >> 16);
}
__device__ __forceinline__ float b2f(unsigned short h) {
    union { unsigned int u; float f; } v; v.u = ((unsigned int)h) << 16;
    return v.f;
}

// ---------------------------------------------------------------------------
// prep: cvec[3][96], wvec[4][96], B-fragment-swizzled bf16 weights.
// BfN: 6 sections (P0,P1,P2,Q0,Q1,Q2) x 3 ksteps x 6 colblocks x 64 lanes x 8
// BfU: 12 ksteps x 6 colblocks x 64 lanes x 8   (Wu 384x96)
// B-frag for mfma_f32_16x16x32_bf16: lane = ((k%32)/8)*16 + (n%16), j = k%8
// ---------------------------------------------------------------------------
__global__ void prep_kernel(const float* Wm0, const float* bm0, const float* ef0,
                            const float* Wm1, const float* bm1, const float* ef1,
                            const float* Wm2, const float* bm2, const float* ef2,
                            const float* Wn0, const float* Wa0,
                            const float* Wn1, const float* Wa1,
                            const float* Wu,
                            float* cvec, float* wvec,
                            unsigned short* BfN, unsigned short* BfU) {
    const float* Wm[3] = {Wm0, Wm1, Wm2};
    const float* bm[3] = {bm0, bm1, bm2};
    const float* ef[3] = {ef0, ef1, ef2};
    const int total = 288 + 384 + 55296 + 36864;
    for (int i = blockIdx.x * blockDim.x + threadIdx.x; i < total;
         i += gridDim.x * blockDim.x) {
        if (i < 288) {
            int t = i / 96, j = i % 96;
            float s = bm[t][j];
            for (int k = 0; k < DE; ++k) s += ef[t][k] * Wm[t][(2 * HH + k) * HH + j];
            cvec[i] = s;
        } else if (i < 288 + 384) {
            int ii = i - 288;
            int kind = ii / 96, k = ii % 96;
            const float* Wn = (kind < 2) ? Wn0 : Wn1;
            const float* Wa = (kind < 2) ? Wa0 : Wa1;
            int off = (kind & 1) ? AD : 0;
            float s = 0.f;
            for (int a = 0; a < AD; ++a) s += Wn[k * AD + a] * Wa[off + a];
            wvec[ii] = s;
        } else if (i < 288 + 384 + 55296) {
            int ii = i - 672;
            int sec = ii / 9216; int rem = ii % 9216;
            int ksc = rem / 512; int lj = rem % 512;
            int ks = ksc / 6, c = ksc % 6;
            int lane = lj / 8, jj = lj % 8;
            int quad = lane / 16, m = lane % 16;
            int k = ks * 32 + quad * 8 + jj;
            int n = c * 16 + m;
            int mt = (sec < 3) ? sec : sec - 3;
            int rowoff = (sec < 3) ? 0 : HH;
            BfN[ii] = f2b(Wm[mt][(rowoff + k) * HH + n]);
        } else {
            int ii = i - (672 + 55296);
            int ksc = ii / 512; int lj = ii % 512;
            int ks = ksc / 6, c = ksc % 6;
            int lane = lj / 8, jj = lj % 8;
            int quad = lane / 16, m = lane % 16;
            int k = ks * 32 + quad * 8 + jj;
            int n = c * 16 + m;
            BfU[ii] = f2b(Wu[k * HH + n]);
        }
    }
}

__global__ void cast_h_kernel(const float* __restrict__ h, unsigned short* __restrict__ hb) {
    const int total = NN * HH;
    for (int i = blockIdx.x * blockDim.x + threadIdx.x; i < total;
         i += gridDim.x * blockDim.x)
        hb[i] = f2b(h[i]);
}

// u0,v0,u1,v1: one 32-lane group per node
__global__ void uv_kernel(const float* __restrict__ h, const float* __restrict__ wvec,
                          float* __restrict__ uv) {
    int lane = threadIdx.x & 31;
    int node = (blockIdx.x * blockDim.x + threadIdx.x) >> 5;
    if (node >= NN) return;
    float h0 = h[node * HH + lane];
    float h1 = h[node * HH + 32 + lane];
    float h2 = h[node * HH + 64 + lane];
    float acc[4];
#pragma unroll
    for (int q = 0; q < 4; ++q)
        acc[q] = h0 * wvec[q * 96 + lane] + h1 * wvec[q * 96 + 32 + lane] +
                 h2 * wvec[q * 96 + 64 + lane];
#pragma unroll
    for (int d = 16; d >= 1; d >>= 1)
#pragma unroll
        for (int q = 0; q < 4; ++q) acc[q] += __shfl_down(acc[q], d, 32);
    if (lane == 0) {
#pragma unroll
        for (int q = 0; q < 4; ++q) uv[q * NN + node] = acc[q];
    }
}

__global__ void zero_kernel(float4* __restrict__ p, int n4) {
    for (int i = blockIdx.x * blockDim.x + threadIdx.x; i < n4;
         i += gridDim.x * blockDim.x)
        p[i] = make_float4(0.f, 0.f, 0.f, 0.f);
}

// Per-type P/Q node GEMM: M=100000, K=96, N=96 x 2 sections (y=0 -> P, y=1 -> Q)
__global__ __launch_bounds__(256) void node_gemm_kernel(const unsigned short* __restrict__ hb,
                                                        const unsigned short* __restrict__ BfN,
                                                        int t,
                                                        unsigned short* __restrict__ Pb,
                                                        unsigned short* __restrict__ Qb) {
    int wave = threadIdx.x >> 6;
    int lane = threadIdx.x & 63;
    int quad = lane >> 4, m = lane & 15;
    int blk = blockIdx.x * 4 + wave;
    if (blk >= NN / 16) return;
    int sec = t + 3 * blockIdx.y;                      // P section = t, Q section = t+3
    unsigned short* dst = blockIdx.y ? Qb : Pb;
    int r0 = blk * 16;
    f32x4 acc[6] = {};
    const unsigned short* arow = hb + (size_t)(r0 + m) * HH + quad * 8;
#pragma unroll
    for (int ks = 0; ks < 3; ++ks) {
        bf16x8 af = *(const bf16x8*)(arow + ks * 32);
#pragma unroll
        for (int c = 0; c < 6; ++c) {
            bf16x8 bfv = *(const bf16x8*)(BfN + (((sec * 3 + ks) * 6 + c) << 9) + lane * 8);
            acc[c] = __builtin_amdgcn_mfma_f32_16x16x32_bf16(af, bfv, acc[c], 0, 0, 0);
        }
    }
#pragma unroll
    for (int c = 0; c < 6; ++c)
#pragma unroll
        for (int r = 0; r < 4; ++r) {
            int row = r0 + quad * 4 + r;
            dst[(size_t)row * HH + c * 16 + m] = f2b(acc[c][r]);
        }
}

// attention-type scatter: 32 lanes per edge; acc[d*96+j] += w*P[s][j], den[d] += w
__global__ void scatter_attn_kernel(const int* __restrict__ src, const int* __restrict__ dst,
                                    const float* __restrict__ u, const float* __restrict__ v,
                                    const unsigned short* __restrict__ P,
                                    float* __restrict__ acc, float* __restrict__ den) {
    int lane = threadIdx.x & 31;
    int g = (blockIdx.x * blockDim.x + threadIdx.x) >> 5;
    int ng = (gridDim.x * blockDim.x) >> 5;
    for (int e = g; e < EE; e += ng) {
        int s = src[e], d = dst[e];
        float sc = u[s] + v[d];
        sc = sc > 0.f ? sc : NEG * sc;
        float w = __expf(sc);
        if (lane == 0) atomicAdd(den + d, w);
        float* arow = acc + (size_t)d * HH;
        const unsigned short* prow = P + (size_t)s * HH;
#pragma unroll
        for (int rep = 0; rep < 3; ++rep) {
            int j = lane + rep * 32;
            atomicAdd(arow + j, w * b2f(prow[j]));
        }
    }
}

__global__ void scatter_mean_kernel(const int* __restrict__ src, const int* __restrict__ dst,
                                    const unsigned short* __restrict__ P,
                                    float* __restrict__ acc, float* __restrict__ den) {
    int lane = threadIdx.x & 31;
    int g = (blockIdx.x * blockDim.x + threadIdx.x) >> 5;
    int ng = (gridDim.x * blockDim.x) >> 5;
    for (int e = g; e < EE; e += ng) {
        int s = src[e], d = dst[e];
        if (lane == 0) atomicAdd(den + d, 1.f);
        float* arow = acc + (size_t)d * HH;
        const unsigned short* prow = P + (size_t)s * HH;
#pragma unroll
        for (int rep = 0; rep < 3; ++rep) {
            int j = lane + rep * 32;
            atomicAdd(arow + j, b2f(prow[j]));
        }
    }
}

// msg_t = acc/den + Q + c (0 if den==0), stored bf16 into msgb[:, t*96:(t+1)*96]
__global__ void finalize_kernel(const float* __restrict__ acc, const float* __restrict__ den,
                                const unsigned short* __restrict__ Qb,
                                const float* __restrict__ cvec_t,
                                unsigned short* __restrict__ msgb_t) {
    const int total = NN * HH;
    for (int i = blockIdx.x * blockDim.x + threadIdx.x; i < total;
         i += gridDim.x * blockDim.x) {
        int d = i / HH, j = i % HH;
        float dn = den[d];
        float val = 0.f;
        if (dn > 0.f) val = acc[i] / dn + b2f(Qb[i]) + cvec_t[j];
        msgb_t[(size_t)d * 288 + j] = f2b(val);
    }
}

// out = relu([h | msg] @ Wu + bu): M=100000, K=384, N=96
__global__ __launch_bounds__(256) void update_gemm_kernel(const unsigned short* __restrict__ hb,
                                                          const unsigned short* __restrict__ msgb,
                                                          const unsigned short* __restrict__ BfU,
                                                          const float* __restrict__ bu,
                                                          float* __restrict__ out) {
    int wave = threadIdx.x >> 6;
    int lane = threadIdx.x & 63;
    int quad = lane >> 4, m = lane & 15;
    int blk = blockIdx.x * 4 + wave;
    if (blk >= NN / 16) return;
    int r0 = blk * 16;
    f32x4 acc[6] = {};
#pragma unroll
    for (int ks = 0; ks < 12; ++ks) {
        const unsigned short* ap =
            (ks < 3) ? hb + (size_t)(r0 + m) * HH + ks * 32 + quad * 8
                     : msgb + (size_t)(r0 + m) * 288 + (ks - 3) * 32 + quad * 8;
        bf16x8 af = *(const bf16x8*)ap;
#pragma unroll
        for (int c = 0; c < 6; ++c) {
            bf16x8 bfv = *(const bf16x8*)(BfU + ((ks * 6 + c) << 9) + lane * 8);
            acc[c] = __builtin_amdgcn_mfma_f32_16x16x32_bf16(af, bfv, acc[c], 0, 0, 0);
        }
    }
#pragma unroll
    for (int c = 0; c < 6; ++c) {
        float b = bu[c * 16 + m];
#pragma unroll
        for (int r = 0; r < 4; ++r) {
            int row = r0 + quad * 4 + r;
            float v2 = acc[c][r] + b;
            out[(size_t)row * HH + c * 16 + m] = v2 > 0.f ? v2 : 0.f;
        }
    }
}

extern "C" void kernel_launch(void* const* d_in, const int* in_sizes, int n_in,
                              void* d_out, int out_size, void* d_ws, size_t ws_size,
                              hipStream_t stream) {
    (void)in_sizes; (void)n_in; (void)out_size;
    const float* h   = (const float*)d_in[0];
    const int* srcs[3] = {(const int*)d_in[1], (const int*)d_in[3], (const int*)d_in[5]};
    const int* dsts[3] = {(const int*)d_in[2], (const int*)d_in[4], (const int*)d_in[6]};
    const float* Wm0 = (const float*)d_in[7];
    const float* bm0 = (const float*)d_in[8];
    const float* ef0 = (const float*)d_in[9];
    const float* Wm1 = (const float*)d_in[10];
    const float* bm1 = (const float*)d_in[11];
    const float* ef1 = (const float*)d_in[12];
    const float* Wm2 = (const float*)d_in[13];
    const float* bm2 = (const float*)d_in[14];
    const float* ef2 = (const float*)d_in[15];
    const float* Wn0 = (const float*)d_in[16];
    const float* Wa0 = (const float*)d_in[17];
    const float* Wn1 = (const float*)d_in[18];
    const float* Wa1 = (const float*)d_in[19];
    const float* Wu  = (const float*)d_in[20];
    const float* bu  = (const float*)d_in[21];
    float* out = (float*)d_out;

    // Workspace layout (total 155,787,136 B ~ 155.8 MB; all 16B-aligned)
    const size_t NEED = 155787136;
    if (ws_size < NEED) return;  // fail validation cleanly instead of faulting
    char* w = (char*)d_ws;
    unsigned short* msgb = (unsigned short*)(w + 0);              // N*288 bf16
    unsigned short* hb   = (unsigned short*)(w + 57600000);       // N*96 bf16
    unsigned short* Pb   = (unsigned short*)(w + 76800000);       // N*96 bf16 (per type)
    unsigned short* Qb   = (unsigned short*)(w + 96000000);       // N*96 bf16 (per type)
    float*          acc  = (float*)(w + 115200000);               // N*96 f32 (per type)
    float*          den  = (float*)(w + 153600000);               // N f32 (contig w/ acc)
    float*          uv   = (float*)(w + 154000000);               // 4*N f32
    float*          cvec = (float*)(w + 155600000);               // 288 f32
    float*          wvec = (float*)(w + 155601280);               // 384 f32
    unsigned short* BfN  = (unsigned short*)(w + 155602816);      // 55296 bf16
    unsigned short* BfU  = (unsigned short*)(w + 155713408);      // 36864 bf16

    prep_kernel<<<128, 256, 0, stream>>>(Wm0, bm0, ef0, Wm1, bm1, ef1, Wm2, bm2, ef2,
                                         Wn0, Wa0, Wn1, Wa1, Wu, cvec, wvec, BfN, BfU);
    cast_h_kernel<<<4096, 256, 0, stream>>>(h, hb);
    uv_kernel<<<(NN * 32) / 256, 256, 0, stream>>>(h, wvec, uv);

    for (int t = 0; t < 3; ++t) {
        node_gemm_kernel<<<dim3(1563, 2), 256, 0, stream>>>(hb, BfN, t, Pb, Qb);
        zero_kernel<<<2048, 256, 0, stream>>>((float4*)acc, (NN * HH + NN) / 4);
        if (t < 2)
            scatter_attn_kernel<<<4096, 256, 0, stream>>>(srcs[t], dsts[t],
                                                          uv + 2 * t * NN, uv + (2 * t + 1) * NN,
                                                          Pb, acc, den);
        else
            scatter_mean_kernel<<<4096, 256, 0, stream>>>(srcs[t], dsts[t], Pb, acc, den);
        finalize_kernel<<<4096, 256, 0, stream>>>(acc, den, Qb, cvec + t * 96, msgb + t * 96);
    }

    update_gemm_kernel<<<1563, 256, 0, stream>>>(hb, msgb, BfU, bu, out);
}

// Round 3
// 572.092 us; speedup vs baseline: 1.4734x; 1.4734x over previous
//
#include <hip/hip_runtime.h>
#include <hip/hip_bf16.h>
#include <cstdint>

// Problem constants (fixed by reference)
#define NN 100000
#define HH 96
#define AD 32
#define DE 16
#define EE 500000
#define NEG 0.01f
#define NBLK 98   // ceil(NN/1024)

typedef __bf16 bf16x8 __attribute__((ext_vector_type(8)));
typedef float  f32x4  __attribute__((ext_vector_type(4)));

__device__ __forceinline__ unsigned short f2b(float x) {
    union { float f; unsigned int u; } v; v.f = x;
    unsigned int r = v.u + 0x7fffu + ((v.u >> 16) & 1u);  // RNE
    return (unsigned short)(r >> 16);
}
__device__ __forceinline__ float b2f(unsigned short h) {
    union { unsigned int u; float f; } v; v.u = ((unsigned int)h) << 16;
    return v.f;
}

// ---------------------------------------------------------------------------
// prep: cvec[3][96], wvec[4][96], B-fragment-swizzled bf16 weights.
// BfN: 6 sections (P0,P1,P2,Q0,Q1,Q2) x 3 ksteps x 6 colblocks x 64 lanes x 8
// BfU: 12 ksteps x 6 colblocks x 64 lanes x 8   (Wu 384x96)
// B-frag for mfma_f32_16x16x32_bf16: lane = ((k%32)/8)*16 + (n%16), j = k%8
// ---------------------------------------------------------------------------
__global__ void prep_kernel(const float* Wm0, const float* bm0, const float* ef0,
                            const float* Wm1, const float* bm1, const float* ef1,
                            const float* Wm2, const float* bm2, const float* ef2,
                            const float* Wn0, const float* Wa0,
                            const float* Wn1, const float* Wa1,
                            const float* Wu,
                            float* cvec, float* wvec,
                            unsigned short* BfN, unsigned short* BfU) {
    const float* Wm[3] = {Wm0, Wm1, Wm2};
    const float* bm[3] = {bm0, bm1, bm2};
    const float* ef[3] = {ef0, ef1, ef2};
    const int total = 288 + 384 + 55296 + 36864;
    for (int i = blockIdx.x * blockDim.x + threadIdx.x; i < total;
         i += gridDim.x * blockDim.x) {
        if (i < 288) {
            int t = i / 96, j = i % 96;
            float s = bm[t][j];
            for (int k = 0; k < DE; ++k) s += ef[t][k] * Wm[t][(2 * HH + k) * HH + j];
            cvec[i] = s;
        } else if (i < 288 + 384) {
            int ii = i - 288;
            int kind = ii / 96, k = ii % 96;
            const float* Wn = (kind < 2) ? Wn0 : Wn1;
            const float* Wa = (kind < 2) ? Wa0 : Wa1;
            int off = (kind & 1) ? AD : 0;
            float s = 0.f;
            for (int a = 0; a < AD; ++a) s += Wn[k * AD + a] * Wa[off + a];
            wvec[ii] = s;
        } else if (i < 288 + 384 + 55296) {
            int ii = i - 672;
            int sec = ii / 9216; int rem = ii % 9216;
            int ksc = rem / 512; int lj = rem % 512;
            int ks = ksc / 6, c = ksc % 6;
            int lane = lj / 8, jj = lj % 8;
            int quad = lane / 16, m = lane % 16;
            int k = ks * 32 + quad * 8 + jj;
            int n = c * 16 + m;
            int mt = (sec < 3) ? sec : sec - 3;
            int rowoff = (sec < 3) ? 0 : HH;
            BfN[ii] = f2b(Wm[mt][(rowoff + k) * HH + n]);
        } else {
            int ii = i - (672 + 55296);
            int ksc = ii / 512; int lj = ii % 512;
            int ks = ksc / 6, c = ksc % 6;
            int lane = lj / 8, jj = lj % 8;
            int quad = lane / 16, m = lane % 16;
            int k = ks * 32 + quad * 8 + jj;
            int n = c * 16 + m;
            BfU[ii] = f2b(Wu[k * HH + n]);
        }
    }
}

__global__ void cast_h_kernel(const float* __restrict__ h, unsigned short* __restrict__ hb) {
    const int total = NN * HH;
    for (int i = blockIdx.x * blockDim.x + threadIdx.x; i < total;
         i += gridDim.x * blockDim.x)
        hb[i] = f2b(h[i]);
}

// u0,v0,u1,v1: one 32-lane group per node
__global__ void uv_kernel(const float* __restrict__ h, const float* __restrict__ wvec,
                          float* __restrict__ uv) {
    int lane = threadIdx.x & 31;
    int node = (blockIdx.x * blockDim.x + threadIdx.x) >> 5;
    if (node >= NN) return;
    float h0 = h[node * HH + lane];
    float h1 = h[node * HH + 32 + lane];
    float h2 = h[node * HH + 64 + lane];
    float acc[4];
#pragma unroll
    for (int q = 0; q < 4; ++q)
        acc[q] = h0 * wvec[q * 96 + lane] + h1 * wvec[q * 96 + 32 + lane] +
                 h2 * wvec[q * 96 + 64 + lane];
#pragma unroll
    for (int d = 16; d >= 1; d >>= 1)
#pragma unroll
        for (int q = 0; q < 4; ++q) acc[q] += __shfl_down(acc[q], d, 32);
    if (lane == 0) {
#pragma unroll
        for (int q = 0; q < 4; ++q) uv[q * NN + node] = acc[q];
    }
}

__global__ void zero_kernel(float4* __restrict__ p, int n4) {
    for (int i = blockIdx.x * blockDim.x + threadIdx.x; i < n4;
         i += gridDim.x * blockDim.x)
        p[i] = make_float4(0.f, 0.f, 0.f, 0.f);
}

// ---------------------------------------------------------------------------
// CSR build: histogram -> 3-pass scan -> reorder (atomic bump into slots)
// ---------------------------------------------------------------------------
__global__ void hist_kernel(const int* __restrict__ d0, const int* __restrict__ d1,
                            const int* __restrict__ d2, int* __restrict__ cnt) {
    const int total = 3 * EE;
    for (int i = blockIdx.x * blockDim.x + threadIdx.x; i < total;
         i += gridDim.x * blockDim.x) {
        int t = i / EE, e = i - t * EE;
        const int* d = (t == 0) ? d0 : (t == 1) ? d1 : d2;
        atomicAdd(&cnt[t * NN + d[e]], 1);
    }
}

__global__ void scan_pass1(const int* __restrict__ cnt, int* __restrict__ bsum) {
    __shared__ int red[256];
    int type = blockIdx.x / NBLK, blk = blockIdx.x % NBLK;
    int base = blk * 1024;
    int s = 0;
#pragma unroll
    for (int k = 0; k < 4; ++k) {
        int i = base + k * 256 + threadIdx.x;
        if (i < NN) s += cnt[type * NN + i];
    }
    red[threadIdx.x] = s;
    __syncthreads();
    for (int off = 128; off; off >>= 1) {
        if ((int)threadIdx.x < off) red[threadIdx.x] += red[threadIdx.x + off];
        __syncthreads();
    }
    if (threadIdx.x == 0) bsum[type * NBLK + blk] = red[0];
}

__global__ void scan_pass2(int* __restrict__ bsum, int* __restrict__ rs) {
    int t = threadIdx.x;
    if (t >= 3) return;
    int run = 0;
    for (int b = 0; b < NBLK; ++b) {
        int x = bsum[t * NBLK + b];
        bsum[t * NBLK + b] = run;
        run += x;
    }
    rs[t * (NN + 1) + NN] = run;  // = EE
}

__global__ void scan_pass3(const int* __restrict__ cnt, const int* __restrict__ bsum,
                           int* __restrict__ rs, int* __restrict__ cursor) {
    __shared__ int sums[256];
    int tid = threadIdx.x;
    int type = blockIdx.x / NBLK, blk = blockIdx.x % NBLK;
    int base = blk * 1024 + tid * 4;
    int v[4];
    int s = 0;
#pragma unroll
    for (int k = 0; k < 4; ++k) {
        int i = base + k;
        v[k] = (i < NN) ? cnt[type * NN + i] : 0;
        s += v[k];
    }
    sums[tid] = s;
    __syncthreads();
    for (int off = 1; off < 256; off <<= 1) {
        int add = (tid >= off) ? sums[tid - off] : 0;
        __syncthreads();
        sums[tid] += add;
        __syncthreads();
    }
    int run = bsum[type * NBLK + blk] + sums[tid] - s;  // exclusive prefix for this thread
#pragma unroll
    for (int k = 0; k < 4; ++k) {
        int i = base + k;
        if (i < NN) {
            rs[type * (NN + 1) + i] = run;
            cursor[type * NN + i] = run;
        }
        run += v[k];
    }
}

__global__ void reorder_kernel(const int* __restrict__ s0, const int* __restrict__ d0,
                               const int* __restrict__ s1, const int* __restrict__ d1,
                               const int* __restrict__ s2, const int* __restrict__ d2,
                               int* __restrict__ cursor, int* __restrict__ sorted) {
    const int total = 3 * EE;
    for (int i = blockIdx.x * blockDim.x + threadIdx.x; i < total;
         i += gridDim.x * blockDim.x) {
        int t = i / EE, e = i - t * EE;
        const int* src = (t == 0) ? s0 : (t == 1) ? s1 : s2;
        const int* dst = (t == 0) ? d0 : (t == 1) ? d1 : d2;
        int d = dst[e];
        int pos = atomicAdd(&cursor[t * NN + d], 1);
        sorted[t * EE + pos] = src[e];
    }
}

// Per-type P/Q node GEMM: M=100000, K=96, N=96 x 2 sections (y=0 -> P, y=1 -> Q)
__global__ __launch_bounds__(256) void node_gemm_kernel(const unsigned short* __restrict__ hb,
                                                        const unsigned short* __restrict__ BfN,
                                                        int t,
                                                        unsigned short* __restrict__ Pb,
                                                        unsigned short* __restrict__ Qb) {
    int wave = threadIdx.x >> 6;
    int lane = threadIdx.x & 63;
    int quad = lane >> 4, m = lane & 15;
    int blk = blockIdx.x * 4 + wave;
    if (blk >= NN / 16) return;
    int sec = t + 3 * blockIdx.y;                      // P section = t, Q section = t+3
    unsigned short* dst = blockIdx.y ? Qb : Pb;
    int r0 = blk * 16;
    f32x4 acc[6] = {};
    const unsigned short* arow = hb + (size_t)(r0 + m) * HH + quad * 8;
#pragma unroll
    for (int ks = 0; ks < 3; ++ks) {
        bf16x8 af = *(const bf16x8*)(arow + ks * 32);
#pragma unroll
        for (int c = 0; c < 6; ++c) {
            bf16x8 bfv = *(const bf16x8*)(BfN + (((sec * 3 + ks) * 6 + c) << 9) + lane * 8);
            acc[c] = __builtin_amdgcn_mfma_f32_16x16x32_bf16(af, bfv, acc[c], 0, 0, 0);
        }
    }
#pragma unroll
    for (int c = 0; c < 6; ++c)
#pragma unroll
        for (int r = 0; r < 4; ++r) {
            int row = r0 + quad * 4 + r;
            dst[(size_t)row * HH + c * 16 + m] = f2b(acc[c][r]);
        }
}

// Gather aggregation + fused finalize: one 32-lane group per dst node.
// msg_t[d] = (sum_e w_e * P[src_e]) / (sum_e w_e) + Q[d] + cvec_t  (0 if no edges)
__global__ void aggregate_kernel(const int* __restrict__ rs, const int* __restrict__ sorted,
                                 const float* __restrict__ u, const float* __restrict__ vv,
                                 const unsigned short* __restrict__ P,
                                 const unsigned short* __restrict__ Q,
                                 const float* __restrict__ cvec_t, int is_attn,
                                 unsigned short* __restrict__ msgb_t) {
    int lane = threadIdx.x & 31;
    int node = (blockIdx.x * blockDim.x + threadIdx.x) >> 5;
    if (node >= NN) return;
    int beg = rs[node], end = rs[node + 1];
    float a0 = 0.f, a1 = 0.f, a2 = 0.f, den = 0.f;
    float vd = is_attn ? vv[node] : 0.f;
    for (int i = beg; i < end; ++i) {
        int s = sorted[i];
        float w = 1.f;
        if (is_attn) {
            float sc = u[s] + vd;
            sc = sc > 0.f ? sc : NEG * sc;
            w = __expf(sc);
        }
        den += w;
        const unsigned short* pr = P + (size_t)s * HH;
        a0 += w * b2f(pr[lane]);
        a1 += w * b2f(pr[lane + 32]);
        a2 += w * b2f(pr[lane + 64]);
    }
    float r0 = 0.f, r1 = 0.f, r2 = 0.f;
    if (den > 0.f) {
        float inv = 1.f / den;
        const unsigned short* qr = Q + (size_t)node * HH;
        r0 = a0 * inv + b2f(qr[lane]) + cvec_t[lane];
        r1 = a1 * inv + b2f(qr[lane + 32]) + cvec_t[lane + 32];
        r2 = a2 * inv + b2f(qr[lane + 64]) + cvec_t[lane + 64];
    }
    unsigned short* mr = msgb_t + (size_t)node * 288;
    mr[lane] = f2b(r0);
    mr[lane + 32] = f2b(r1);
    mr[lane + 64] = f2b(r2);
}

// out = relu([h | msg] @ Wu + bu): M=100000, K=384, N=96
__global__ __launch_bounds__(256) void update_gemm_kernel(const unsigned short* __restrict__ hb,
                                                          const unsigned short* __restrict__ msgb,
                                                          const unsigned short* __restrict__ BfU,
                                                          const float* __restrict__ bu,
                                                          float* __restrict__ out) {
    int wave = threadIdx.x >> 6;
    int lane = threadIdx.x & 63;
    int quad = lane >> 4, m = lane & 15;
    int blk = blockIdx.x * 4 + wave;
    if (blk >= NN / 16) return;
    int r0 = blk * 16;
    f32x4 acc[6] = {};
#pragma unroll
    for (int ks = 0; ks < 12; ++ks) {
        const unsigned short* ap =
            (ks < 3) ? hb + (size_t)(r0 + m) * HH + ks * 32 + quad * 8
                     : msgb + (size_t)(r0 + m) * 288 + (ks - 3) * 32 + quad * 8;
        bf16x8 af = *(const bf16x8*)ap;
#pragma unroll
        for (int c = 0; c < 6; ++c) {
            bf16x8 bfv = *(const bf16x8*)(BfU + ((ks * 6 + c) << 9) + lane * 8);
            acc[c] = __builtin_amdgcn_mfma_f32_16x16x32_bf16(af, bfv, acc[c], 0, 0, 0);
        }
    }
#pragma unroll
    for (int c = 0; c < 6; ++c) {
        float b = bu[c * 16 + m];
#pragma unroll
        for (int r = 0; r < 4; ++r) {
            int row = r0 + quad * 4 + r;
            float v2 = acc[c][r] + b;
            out[(size_t)row * HH + c * 16 + m] = v2 > 0.f ? v2 : 0.f;
        }
    }
}

extern "C" void kernel_launch(void* const* d_in, const int* in_sizes, int n_in,
                              void* d_out, int out_size, void* d_ws, size_t ws_size,
                              hipStream_t stream) {
    (void)in_sizes; (void)n_in; (void)out_size;
    const float* h   = (const float*)d_in[0];
    const int* srcs[3] = {(const int*)d_in[1], (const int*)d_in[3], (const int*)d_in[5]};
    const int* dsts[3] = {(const int*)d_in[2], (const int*)d_in[4], (const int*)d_in[6]};
    const float* Wm0 = (const float*)d_in[7];
    const float* bm0 = (const float*)d_in[8];
    const float* ef0 = (const float*)d_in[9];
    const float* Wm1 = (const float*)d_in[10];
    const float* bm1 = (const float*)d_in[11];
    const float* ef1 = (const float*)d_in[12];
    const float* Wm2 = (const float*)d_in[13];
    const float* bm2 = (const float*)d_in[14];
    const float* ef2 = (const float*)d_in[15];
    const float* Wn0 = (const float*)d_in[16];
    const float* Wa0 = (const float*)d_in[17];
    const float* Wn1 = (const float*)d_in[18];
    const float* Wa1 = (const float*)d_in[19];
    const float* Wu  = (const float*)d_in[20];
    const float* bu  = (const float*)d_in[21];
    float* out = (float*)d_out;

    // Workspace layout (total ~126.6 MB; run 2 proved ws_size >= 155.8 MB)
    const size_t NEED = 126600000;
    if (ws_size < NEED) return;  // fail validation cleanly instead of faulting
    char* w = (char*)d_ws;
    unsigned short* msgb   = (unsigned short*)(w + 0);            // N*288 bf16
    unsigned short* hb     = (unsigned short*)(w + 57600000);     // N*96 bf16
    unsigned short* Pb     = (unsigned short*)(w + 76800000);     // N*96 bf16 (per type)
    unsigned short* Qb     = (unsigned short*)(w + 96000000);     // N*96 bf16 (per type)
    float*          uv     = (float*)(w + 115200000);             // 4*N f32
    float*          cvec   = (float*)(w + 116800000);             // 288 f32
    float*          wvec   = (float*)(w + 116801280);             // 384 f32
    unsigned short* BfN    = (unsigned short*)(w + 116802816);    // 55296 bf16
    unsigned short* BfU    = (unsigned short*)(w + 116913408);    // 36864 bf16
    int*            cnt    = (int*)(w + 116987136);               // 3*N int
    int*            rs     = (int*)(w + 118187136);               // 3*(N+1) int
    int*            cursor = (int*)(w + 119387264);               // 3*N int
    int*            sorted = (int*)(w + 120587264);               // 3*E int
    int*            bsum   = (int*)(w + 126587264);               // 3*NBLK int

    prep_kernel<<<128, 256, 0, stream>>>(Wm0, bm0, ef0, Wm1, bm1, ef1, Wm2, bm2, ef2,
                                         Wn0, Wa0, Wn1, Wa1, Wu, cvec, wvec, BfN, BfU);
    cast_h_kernel<<<4096, 256, 0, stream>>>(h, hb);
    uv_kernel<<<12500, 256, 0, stream>>>(h, wvec, uv);

    // CSR build for all 3 edge types
    zero_kernel<<<512, 256, 0, stream>>>((float4*)cnt, (3 * NN * 4) / 16);
    hist_kernel<<<4096, 256, 0, stream>>>(dsts[0], dsts[1], dsts[2], cnt);
    scan_pass1<<<3 * NBLK, 256, 0, stream>>>(cnt, bsum);
    scan_pass2<<<1, 64, 0, stream>>>(bsum, rs);
    scan_pass3<<<3 * NBLK, 256, 0, stream>>>(cnt, bsum, rs, cursor);
    reorder_kernel<<<4096, 256, 0, stream>>>(srcs[0], dsts[0], srcs[1], dsts[1],
                                             srcs[2], dsts[2], cursor, sorted);

    for (int t = 0; t < 3; ++t) {
        node_gemm_kernel<<<dim3(1563, 2), 256, 0, stream>>>(hb, BfN, t, Pb, Qb);
        aggregate_kernel<<<12500, 256, 0, stream>>>(rs + t * (NN + 1), sorted + t * EE,
                                                    uv + 2 * t * NN, uv + (2 * t + 1) * NN,
                                                    Pb, Qb, cvec + t * 96, (t < 2) ? 1 : 0,
                                                    msgb + t * 96);
    }

    update_gemm_kernel<<<1563, 256, 0, stream>>>(hb, msgb, BfU, bu, out);
}

// Round 4
// 438.957 us; speedup vs baseline: 1.9203x; 1.3033x over previous
//
#include <hip/hip_runtime.h>
#include <hip/hip_bf16.h>
#include <cstdint>

// Problem constants (fixed by reference)
#define NN 100000
#define HH 96
#define AD 32
#define DE 16
#define EE 500000
#define NEG 0.01f

// Bucketing: 98 buckets of 1024 nodes per edge type
#define GSH 10
#define GSZ 1024
#define KB 98
#define CH 4096
#define BPT 123   // ceil(EE/CH)

typedef __bf16 bf16x8 __attribute__((ext_vector_type(8)));
typedef float  f32x4  __attribute__((ext_vector_type(4)));

__device__ __forceinline__ unsigned short f2b(float x) {
    union { float f; unsigned int u; } v; v.f = x;
    unsigned int r = v.u + 0x7fffu + ((v.u >> 16) & 1u);  // RNE
    return (unsigned short)(r >> 16);
}
__device__ __forceinline__ float b2f(unsigned short h) {
    union { unsigned int u; float f; } v; v.u = ((unsigned int)h) << 16;
    return v.f;
}

// ---------------------------------------------------------------------------
// prep: cvec[3][96], wvec[4][96], B-fragment-swizzled bf16 weights.
// BfN: 6 sections (P0,P1,P2,Q0,Q1,Q2) x 3 ksteps x 6 colblocks x 64 lanes x 8
// BfU: 12 ksteps x 6 colblocks x 64 lanes x 8   (Wu 384x96)
// B-frag for mfma_f32_16x16x32_bf16: lane = ((k%32)/8)*16 + (n%16), j = k%8
// ---------------------------------------------------------------------------
__global__ void prep_kernel(const float* Wm0, const float* bm0, const float* ef0,
                            const float* Wm1, const float* bm1, const float* ef1,
                            const float* Wm2, const float* bm2, const float* ef2,
                            const float* Wn0, const float* Wa0,
                            const float* Wn1, const float* Wa1,
                            const float* Wu,
                            float* cvec, float* wvec,
                            unsigned short* BfN, unsigned short* BfU) {
    const float* Wm[3] = {Wm0, Wm1, Wm2};
    const float* bm[3] = {bm0, bm1, bm2};
    const float* ef[3] = {ef0, ef1, ef2};
    const int total = 288 + 384 + 55296 + 36864;
    for (int i = blockIdx.x * blockDim.x + threadIdx.x; i < total;
         i += gridDim.x * blockDim.x) {
        if (i < 288) {
            int t = i / 96, j = i % 96;
            float s = bm[t][j];
            for (int k = 0; k < DE; ++k) s += ef[t][k] * Wm[t][(2 * HH + k) * HH + j];
            cvec[i] = s;
        } else if (i < 288 + 384) {
            int ii = i - 288;
            int kind = ii / 96, k = ii % 96;
            const float* Wn = (kind < 2) ? Wn0 : Wn1;
            const float* Wa = (kind < 2) ? Wa0 : Wa1;
            int off = (kind & 1) ? AD : 0;
            float s = 0.f;
            for (int a = 0; a < AD; ++a) s += Wn[k * AD + a] * Wa[off + a];
            wvec[ii] = s;
        } else if (i < 288 + 384 + 55296) {
            int ii = i - 672;
            int sec = ii / 9216; int rem = ii % 9216;
            int ksc = rem / 512; int lj = rem % 512;
            int ks = ksc / 6, c = ksc % 6;
            int lane = lj / 8, jj = lj % 8;
            int quad = lane / 16, m = lane % 16;
            int k = ks * 32 + quad * 8 + jj;
            int n = c * 16 + m;
            int mt = (sec < 3) ? sec : sec - 3;
            int rowoff = (sec < 3) ? 0 : HH;
            BfN[ii] = f2b(Wm[mt][(rowoff + k) * HH + n]);
        } else {
            int ii = i - (672 + 55296);
            int ksc = ii / 512; int lj = ii % 512;
            int ks = ksc / 6, c = ksc % 6;
            int lane = lj / 8, jj = lj % 8;
            int quad = lane / 16, m = lane % 16;
            int k = ks * 32 + quad * 8 + jj;
            int n = c * 16 + m;
            BfU[ii] = f2b(Wu[k * HH + n]);
        }
    }
}

__global__ void cast_h_kernel(const float* __restrict__ h, unsigned short* __restrict__ hb) {
    const int total = NN * HH;
    for (int i = blockIdx.x * blockDim.x + threadIdx.x; i < total;
         i += gridDim.x * blockDim.x)
        hb[i] = f2b(h[i]);
}

// u0,v0,u1,v1: one 32-lane group per node
__global__ void uv_kernel(const float* __restrict__ h, const float* __restrict__ wvec,
                          float* __restrict__ uv) {
    int lane = threadIdx.x & 31;
    int node = (blockIdx.x * blockDim.x + threadIdx.x) >> 5;
    if (node >= NN) return;
    float h0 = h[node * HH + lane];
    float h1 = h[node * HH + 32 + lane];
    float h2 = h[node * HH + 64 + lane];
    float acc[4];
#pragma unroll
    for (int q = 0; q < 4; ++q)
        acc[q] = h0 * wvec[q * 96 + lane] + h1 * wvec[q * 96 + 32 + lane] +
                 h2 * wvec[q * 96 + 64 + lane];
#pragma unroll
    for (int d = 16; d >= 1; d >>= 1)
#pragma unroll
        for (int q = 0; q < 4; ++q) acc[q] += __shfl_down(acc[q], d, 32);
    if (lane == 0) {
#pragma unroll
        for (int q = 0; q < 4; ++q) uv[q * NN + node] = acc[q];
    }
}

__global__ void zero_kernel(float4* __restrict__ p, int n4) {
    for (int i = blockIdx.x * blockDim.x + threadIdx.x; i < n4;
         i += gridDim.x * blockDim.x)
        p[i] = make_float4(0.f, 0.f, 0.f, 0.f);
}

// ---------------------------------------------------------------------------
// Two-level CSR build: bucket hist -> scan -> LDS-ranked scatter (line-dense
// runs) -> per-bucket counting sort confined to one CU's L2 span.
// ---------------------------------------------------------------------------
__global__ void bucket_hist(const int* __restrict__ d0, const int* __restrict__ d1,
                            const int* __restrict__ d2, int* __restrict__ bCnt) {
    __shared__ int hist[3 * KB];
    int t = threadIdx.x;
    for (int j = t; j < 3 * KB; j += 256) hist[j] = 0;
    __syncthreads();
    const int total = 3 * EE;
    for (int i = blockIdx.x * blockDim.x + t; i < total; i += gridDim.x * blockDim.x) {
        int ty = i / EE, e = i - ty * EE;
        const int* d = (ty == 0) ? d0 : (ty == 1) ? d1 : d2;
        atomicAdd(&hist[ty * KB + (d[e] >> GSH)], 1);
    }
    __syncthreads();
    for (int j = t; j < 3 * KB; j += 256)
        if (hist[j]) atomicAdd(&bCnt[j], hist[j]);
}

__global__ void bucket_scan(const int* __restrict__ bCnt, int* __restrict__ bBase,
                            int* __restrict__ gCursor, int* __restrict__ rs) {
    __shared__ int hist[3 * KB];
    int t = threadIdx.x;
    if (t < 3 * KB) hist[t] = bCnt[t];
    __syncthreads();
    if (t < 3) {
        int run = 0;
        for (int b = 0; b < KB; ++b) {
            bBase[t * (KB + 1) + b] = run;
            gCursor[t * KB + b] = run;
            run += hist[t * KB + b];
        }
        bBase[t * (KB + 1) + KB] = run;           // == EE
        rs[(size_t)t * (NN + 1) + NN] = run;
    }
}

__global__ __launch_bounds__(256) void bucket_scatter(
    const int* __restrict__ s0, const int* __restrict__ d0,
    const int* __restrict__ s1, const int* __restrict__ d1,
    const int* __restrict__ s2, const int* __restrict__ d2,
    int* __restrict__ gCursor, unsigned int* __restrict__ binned) {
    __shared__ unsigned int recs[CH];
    __shared__ unsigned short rnk[CH];
    __shared__ unsigned char bkt[CH];
    __shared__ int cnt[KB];
    __shared__ int gpos[KB];
    int t = threadIdx.x;
    int type = blockIdx.x / BPT;
    int chunk = (blockIdx.x % BPT) * CH;
    const int* src = (type == 0) ? s0 : (type == 1) ? s1 : s2;
    const int* dst = (type == 0) ? d0 : (type == 1) ? d1 : d2;
    if (t < KB) cnt[t] = 0;
    __syncthreads();
#pragma unroll
    for (int k = 0; k < CH / 256; ++k) {
        int idx = k * 256 + t;
        int e = chunk + idx;
        if (e < EE) {
            int s = src[e], d = dst[e];
            int b = d >> GSH;
            recs[idx] = ((unsigned int)s << GSH) | (unsigned int)(d & (GSZ - 1));
            bkt[idx] = (unsigned char)b;
            rnk[idx] = (unsigned short)atomicAdd(&cnt[b], 1);
        } else {
            bkt[idx] = 0xFF;
        }
    }
    __syncthreads();
    if (t < KB) {
        int c = cnt[t];
        gpos[t] = (c > 0) ? atomicAdd(&gCursor[type * KB + t], c) : 0;
    }
    __syncthreads();
    unsigned int* bout = binned + (size_t)type * EE;
#pragma unroll
    for (int k = 0; k < CH / 256; ++k) {
        int idx = k * 256 + t;
        unsigned char b = bkt[idx];
        if (b != 0xFF) bout[gpos[b] + rnk[idx]] = recs[idx];
    }
}

__global__ __launch_bounds__(256) void bucket_sort(
    const unsigned int* __restrict__ binned, const int* __restrict__ bBase,
    int* __restrict__ rs, int* __restrict__ sorted) {
    __shared__ int cnt[GSZ];
    __shared__ int tsum[256];
    int t = threadIdx.x;
    int type = blockIdx.x / KB;
    int b = blockIdx.x % KB;
    int nodeBase = b * GSZ;
    int eb = bBase[type * (KB + 1) + b];
    int en = bBase[type * (KB + 1) + b + 1];
    int n = en - eb;
    const unsigned int* bin = binned + (size_t)type * EE + eb;
#pragma unroll
    for (int k = 0; k < GSZ / 256; ++k) cnt[k * 256 + t] = 0;
    __syncthreads();
    for (int i = t; i < n; i += 256) atomicAdd(&cnt[bin[i] & (GSZ - 1)], 1);
    __syncthreads();
    int v[4], s = 0;
#pragma unroll
    for (int k = 0; k < 4; ++k) { v[k] = cnt[t * 4 + k]; s += v[k]; }
    tsum[t] = s;
    __syncthreads();
    for (int off = 1; off < 256; off <<= 1) {
        int add = (t >= off) ? tsum[t - off] : 0;
        __syncthreads();
        tsum[t] += add;
        __syncthreads();
    }
    int run = tsum[t] - s;  // exclusive base for this thread's 4 nodes
    int offk[4];
#pragma unroll
    for (int k = 0; k < 4; ++k) { offk[k] = run; run += v[k]; }
    int* rsrow = rs + (size_t)type * (NN + 1) + nodeBase;
#pragma unroll
    for (int k = 0; k < 4; ++k) {
        int node = t * 4 + k;
        if (nodeBase + node < NN) rsrow[node] = eb + offk[k];
    }
    __syncthreads();  // all cnt reads done before overwrite
#pragma unroll
    for (int k = 0; k < 4; ++k) cnt[t * 4 + k] = offk[k];
    __syncthreads();
    int* so = sorted + (size_t)type * EE + eb;
    for (int i = t; i < n; i += 256) {
        unsigned int r = bin[i];
        int dl = r & (GSZ - 1);
        int p = atomicAdd(&cnt[dl], 1);
        so[p] = (int)(r >> GSH);
    }
}

// Per-type P/Q node GEMM: M=100000, K=96, N=96 x 2 sections (y=0 -> P, y=1 -> Q)
__global__ __launch_bounds__(256) void node_gemm_kernel(const unsigned short* __restrict__ hb,
                                                        const unsigned short* __restrict__ BfN,
                                                        int t,
                                                        unsigned short* __restrict__ Pb,
                                                        unsigned short* __restrict__ Qb) {
    int wave = threadIdx.x >> 6;
    int lane = threadIdx.x & 63;
    int quad = lane >> 4, m = lane & 15;
    int blk = blockIdx.x * 4 + wave;
    if (blk >= NN / 16) return;
    int sec = t + 3 * blockIdx.y;                      // P section = t, Q section = t+3
    unsigned short* dst = blockIdx.y ? Qb : Pb;
    int r0 = blk * 16;
    f32x4 acc[6] = {};
    const unsigned short* arow = hb + (size_t)(r0 + m) * HH + quad * 8;
#pragma unroll
    for (int ks = 0; ks < 3; ++ks) {
        bf16x8 af = *(const bf16x8*)(arow + ks * 32);
#pragma unroll
        for (int c = 0; c < 6; ++c) {
            bf16x8 bfv = *(const bf16x8*)(BfN + (((sec * 3 + ks) * 6 + c) << 9) + lane * 8);
            acc[c] = __builtin_amdgcn_mfma_f32_16x16x32_bf16(af, bfv, acc[c], 0, 0, 0);
        }
    }
#pragma unroll
    for (int c = 0; c < 6; ++c)
#pragma unroll
        for (int r = 0; r < 4; ++r) {
            int row = r0 + quad * 4 + r;
            dst[(size_t)row * HH + c * 16 + m] = f2b(acc[c][r]);
        }
}

// Gather aggregation + fused finalize: one 32-lane group per dst node.
// msg_t[d] = (sum_e w_e * P[src_e]) / (sum_e w_e) + Q[d] + cvec_t  (0 if no edges)
__global__ void aggregate_kernel(const int* __restrict__ rs, const int* __restrict__ sorted,
                                 const float* __restrict__ u, const float* __restrict__ vv,
                                 const unsigned short* __restrict__ P,
                                 const unsigned short* __restrict__ Q,
                                 const float* __restrict__ cvec_t, int is_attn,
                                 unsigned short* __restrict__ msgb_t) {
    int lane = threadIdx.x & 31;
    int node = (blockIdx.x * blockDim.x + threadIdx.x) >> 5;
    if (node >= NN) return;
    int beg = rs[node], end = rs[node + 1];
    float a0 = 0.f, a1 = 0.f, a2 = 0.f, den = 0.f;
    float vd = is_attn ? vv[node] : 0.f;
    for (int i = beg; i < end; ++i) {
        int s = sorted[i];
        float w = 1.f;
        if (is_attn) {
            float sc = u[s] + vd;
            sc = sc > 0.f ? sc : NEG * sc;
            w = __expf(sc);
        }
        den += w;
        const unsigned short* pr = P + (size_t)s * HH;
        a0 += w * b2f(pr[lane]);
        a1 += w * b2f(pr[lane + 32]);
        a2 += w * b2f(pr[lane + 64]);
    }
    float r0 = 0.f, r1 = 0.f, r2 = 0.f;
    if (den > 0.f) {
        float inv = 1.f / den;
        const unsigned short* qr = Q + (size_t)node * HH;
        r0 = a0 * inv + b2f(qr[lane]) + cvec_t[lane];
        r1 = a1 * inv + b2f(qr[lane + 32]) + cvec_t[lane + 32];
        r2 = a2 * inv + b2f(qr[lane + 64]) + cvec_t[lane + 64];
    }
    unsigned short* mr = msgb_t + (size_t)node * 288;
    mr[lane] = f2b(r0);
    mr[lane + 32] = f2b(r1);
    mr[lane + 64] = f2b(r2);
}

// out = relu([h | msg] @ Wu + bu): M=100000, K=384, N=96
__global__ __launch_bounds__(256) void update_gemm_kernel(const unsigned short* __restrict__ hb,
                                                          const unsigned short* __restrict__ msgb,
                                                          const unsigned short* __restrict__ BfU,
                                                          const float* __restrict__ bu,
                                                          float* __restrict__ out) {
    int wave = threadIdx.x >> 6;
    int lane = threadIdx.x & 63;
    int quad = lane >> 4, m = lane & 15;
    int blk = blockIdx.x * 4 + wave;
    if (blk >= NN / 16) return;
    int r0 = blk * 16;
    f32x4 acc[6] = {};
#pragma unroll
    for (int ks = 0; ks < 12; ++ks) {
        const unsigned short* ap =
            (ks < 3) ? hb + (size_t)(r0 + m) * HH + ks * 32 + quad * 8
                     : msgb + (size_t)(r0 + m) * 288 + (ks - 3) * 32 + quad * 8;
        bf16x8 af = *(const bf16x8*)ap;
#pragma unroll
        for (int c = 0; c < 6; ++c) {
            bf16x8 bfv = *(const bf16x8*)(BfU + ((ks * 6 + c) << 9) + lane * 8);
            acc[c] = __builtin_amdgcn_mfma_f32_16x16x32_bf16(af, bfv, acc[c], 0, 0, 0);
        }
    }
#pragma unroll
    for (int c = 0; c < 6; ++c) {
        float b = bu[c * 16 + m];
#pragma unroll
        for (int r = 0; r < 4; ++r) {
            int row = r0 + quad * 4 + r;
            float v2 = acc[c][r] + b;
            out[(size_t)row * HH + c * 16 + m] = v2 > 0.f ? v2 : 0.f;
        }
    }
}

extern "C" void kernel_launch(void* const* d_in, const int* in_sizes, int n_in,
                              void* d_out, int out_size, void* d_ws, size_t ws_size,
                              hipStream_t stream) {
    (void)in_sizes; (void)n_in; (void)out_size;
    const float* h   = (const float*)d_in[0];
    const int* srcs[3] = {(const int*)d_in[1], (const int*)d_in[3], (const int*)d_in[5]};
    const int* dsts[3] = {(const int*)d_in[2], (const int*)d_in[4], (const int*)d_in[6]};
    const float* Wm0 = (const float*)d_in[7];
    const float* bm0 = (const float*)d_in[8];
    const float* ef0 = (const float*)d_in[9];
    const float* Wm1 = (const float*)d_in[10];
    const float* bm1 = (const float*)d_in[11];
    const float* ef1 = (const float*)d_in[12];
    const float* Wm2 = (const float*)d_in[13];
    const float* bm2 = (const float*)d_in[14];
    const float* ef2 = (const float*)d_in[15];
    const float* Wn0 = (const float*)d_in[16];
    const float* Wa0 = (const float*)d_in[17];
    const float* Wn1 = (const float*)d_in[18];
    const float* Wa1 = (const float*)d_in[19];
    const float* Wu  = (const float*)d_in[20];
    const float* bu  = (const float*)d_in[21];
    float* out = (float*)d_out;

    // Workspace layout (total ~130.2 MB; run 2 proved ws_size >= 155.8 MB)
    const size_t NEED = 130191104;
    if (ws_size < NEED) return;  // fail validation cleanly instead of faulting
    char* w = (char*)d_ws;
    unsigned short* msgb    = (unsigned short*)(w + 0);            // N*288 bf16
    unsigned short* hb      = (unsigned short*)(w + 57600000);     // N*96 bf16
    unsigned short* Pb      = (unsigned short*)(w + 76800000);     // N*96 bf16 (per type)
    unsigned short* Qb      = (unsigned short*)(w + 96000000);     // N*96 bf16 (per type)
    float*          uv      = (float*)(w + 115200000);             // 4*N f32
    float*          cvec    = (float*)(w + 116800000);             // 288 f32
    float*          wvec    = (float*)(w + 116801280);             // 384 f32
    unsigned short* BfN     = (unsigned short*)(w + 116802816);    // 55296 bf16
    unsigned short* BfU     = (unsigned short*)(w + 116913408);    // 36864 bf16
    int*            bBase   = (int*)(w + 116987136);               // 3*(KB+1) int
    int*            gCursor = (int*)(w + 116988416);               // 3*KB int
    int*            bCnt    = (int*)(w + 116989696);               // 3*KB int
    int*            rs      = (int*)(w + 116990976);               // 3*(N+1) int
    int*            sorted  = (int*)(w + 118191104);               // 3*E int
    unsigned int*   binned  = (unsigned int*)(w + 124191104);      // 3*E u32

    prep_kernel<<<128, 256, 0, stream>>>(Wm0, bm0, ef0, Wm1, bm1, ef1, Wm2, bm2, ef2,
                                         Wn0, Wa0, Wn1, Wa1, Wu, cvec, wvec, BfN, BfU);
    cast_h_kernel<<<4096, 256, 0, stream>>>(h, hb);
    uv_kernel<<<12500, 256, 0, stream>>>(h, wvec, uv);

    // CSR build for all 3 edge types (bucketed two-level sort)
    zero_kernel<<<1, 256, 0, stream>>>((float4*)bCnt, 80);
    bucket_hist<<<512, 256, 0, stream>>>(dsts[0], dsts[1], dsts[2], bCnt);
    bucket_scan<<<1, 384, 0, stream>>>(bCnt, bBase, gCursor, rs);
    bucket_scatter<<<3 * BPT, 256, 0, stream>>>(srcs[0], dsts[0], srcs[1], dsts[1],
                                                srcs[2], dsts[2], gCursor, binned);
    bucket_sort<<<3 * KB, 256, 0, stream>>>(binned, bBase, rs, sorted);

    for (int t = 0; t < 3; ++t) {
        node_gemm_kernel<<<dim3(1563, 2), 256, 0, stream>>>(hb, BfN, t, Pb, Qb);
        aggregate_kernel<<<12500, 256, 0, stream>>>(rs + t * (NN + 1), sorted + t * EE,
                                                    uv + 2 * t * NN, uv + (2 * t + 1) * NN,
                                                    Pb, Qb, cvec + t * 96, (t < 2) ? 1 : 0,
                                                    msgb + t * 96);
    }

    update_gemm_kernel<<<1563, 256, 0, stream>>>(hb, msgb, BfU, bu, out);
}

// Round 5
// 363.279 us; speedup vs baseline: 2.3203x; 1.2083x over previous
//
#include <hip/hip_runtime.h>
#include <hip/hip_bf16.h>
#include <cstdint>

// Problem constants (fixed by reference)
#define NN 100000
#define HH 96
#define AD 32
#define DE 16
#define EE 500000
#define NEG 0.01f

// Bucketing: 98 buckets of 1024 nodes per edge type
#define GSH 10
#define GSZ 1024
#define KB 98
#define CH 4096
#define BPT 123   // ceil(EE/CH)

typedef __bf16 bf16x8 __attribute__((ext_vector_type(8)));
typedef float  f32x4  __attribute__((ext_vector_type(4)));

__device__ __forceinline__ unsigned short f2b(float x) {
    union { float f; unsigned int u; } v; v.f = x;
    unsigned int r = v.u + 0x7fffu + ((v.u >> 16) & 1u);  // RNE
    return (unsigned short)(r >> 16);
}
__device__ __forceinline__ float b2f(unsigned short h) {
    union { unsigned int u; float f; } v; v.u = ((unsigned int)h) << 16;
    return v.f;
}

// ---------------------------------------------------------------------------
// prep: cvec[3][96], wvec[4][96], B-fragment-swizzled bf16 weights.
// BfN: 6 sections (P0,P1,P2,Q0,Q1,Q2) x 3 ksteps x 6 colblocks x 64 lanes x 8
// BfU: 12 ksteps x 6 colblocks x 64 lanes x 8   (Wu 384x96)
// B-frag for mfma_f32_16x16x32_bf16: lane = ((k%32)/8)*16 + (n%16), j = k%8
// ---------------------------------------------------------------------------
__global__ void prep_kernel(const float* Wm0, const float* bm0, const float* ef0,
                            const float* Wm1, const float* bm1, const float* ef1,
                            const float* Wm2, const float* bm2, const float* ef2,
                            const float* Wn0, const float* Wa0,
                            const float* Wn1, const float* Wa1,
                            const float* Wu,
                            float* cvec, float* wvec,
                            unsigned short* BfN, unsigned short* BfU) {
    const float* Wm[3] = {Wm0, Wm1, Wm2};
    const float* bm[3] = {bm0, bm1, bm2};
    const float* ef[3] = {ef0, ef1, ef2};
    const int total = 288 + 384 + 55296 + 36864;
    for (int i = blockIdx.x * blockDim.x + threadIdx.x; i < total;
         i += gridDim.x * blockDim.x) {
        if (i < 288) {
            int t = i / 96, j = i % 96;
            float s = bm[t][j];
            for (int k = 0; k < DE; ++k) s += ef[t][k] * Wm[t][(2 * HH + k) * HH + j];
            cvec[i] = s;
        } else if (i < 288 + 384) {
            int ii = i - 288;
            int kind = ii / 96, k = ii % 96;
            const float* Wn = (kind < 2) ? Wn0 : Wn1;
            const float* Wa = (kind < 2) ? Wa0 : Wa1;
            int off = (kind & 1) ? AD : 0;
            float s = 0.f;
            for (int a = 0; a < AD; ++a) s += Wn[k * AD + a] * Wa[off + a];
            wvec[ii] = s;
        } else if (i < 288 + 384 + 55296) {
            int ii = i - 672;
            int sec = ii / 9216; int rem = ii % 9216;
            int ksc = rem / 512; int lj = rem % 512;
            int ks = ksc / 6, c = ksc % 6;
            int lane = lj / 8, jj = lj % 8;
            int quad = lane / 16, m = lane % 16;
            int k = ks * 32 + quad * 8 + jj;
            int n = c * 16 + m;
            int mt = (sec < 3) ? sec : sec - 3;
            int rowoff = (sec < 3) ? 0 : HH;
            BfN[ii] = f2b(Wm[mt][(rowoff + k) * HH + n]);
        } else {
            int ii = i - (672 + 55296);
            int ksc = ii / 512; int lj = ii % 512;
            int ks = ksc / 6, c = ksc % 6;
            int lane = lj / 8, jj = lj % 8;
            int quad = lane / 16, m = lane % 16;
            int k = ks * 32 + quad * 8 + jj;
            int n = c * 16 + m;
            BfU[ii] = f2b(Wu[k * HH + n]);
        }
    }
}

// Fused: bf16 cast of h + u/v attention pre-dots. One 32-lane group per node.
__global__ void cast_uv_kernel(const float* __restrict__ h, const float* __restrict__ wvec,
                               unsigned short* __restrict__ hb, float* __restrict__ uv) {
    int lane = threadIdx.x & 31;
    int node = (blockIdx.x * blockDim.x + threadIdx.x) >> 5;
    if (node >= NN) return;
    float h0 = h[node * HH + lane];
    float h1 = h[node * HH + 32 + lane];
    float h2 = h[node * HH + 64 + lane];
    hb[node * HH + lane] = f2b(h0);
    hb[node * HH + 32 + lane] = f2b(h1);
    hb[node * HH + 64 + lane] = f2b(h2);
    float acc[4];
#pragma unroll
    for (int q = 0; q < 4; ++q)
        acc[q] = h0 * wvec[q * 96 + lane] + h1 * wvec[q * 96 + 32 + lane] +
                 h2 * wvec[q * 96 + 64 + lane];
#pragma unroll
    for (int d = 16; d >= 1; d >>= 1)
#pragma unroll
        for (int q = 0; q < 4; ++q) acc[q] += __shfl_down(acc[q], d, 32);
    if (lane == 0) {
#pragma unroll
        for (int q = 0; q < 4; ++q) uv[q * NN + node] = acc[q];
    }
}

__global__ void zero_kernel(float4* __restrict__ p, int n4) {
    for (int i = blockIdx.x * blockDim.x + threadIdx.x; i < n4;
         i += gridDim.x * blockDim.x)
        p[i] = make_float4(0.f, 0.f, 0.f, 0.f);
}

// ---------------------------------------------------------------------------
// Two-level CSR build: bucket hist -> scan -> LDS-ranked scatter (line-dense
// runs) -> per-bucket counting sort confined to one CU's L2 span.
// ---------------------------------------------------------------------------
__global__ void bucket_hist(const int* __restrict__ d0, const int* __restrict__ d1,
                            const int* __restrict__ d2, int* __restrict__ bCnt) {
    __shared__ int hist[3 * KB];
    int t = threadIdx.x;
    for (int j = t; j < 3 * KB; j += 256) hist[j] = 0;
    __syncthreads();
    const int total = 3 * EE;
    for (int i = blockIdx.x * blockDim.x + t; i < total; i += gridDim.x * blockDim.x) {
        int ty = i / EE, e = i - ty * EE;
        const int* d = (ty == 0) ? d0 : (ty == 1) ? d1 : d2;
        atomicAdd(&hist[ty * KB + (d[e] >> GSH)], 1);
    }
    __syncthreads();
    for (int j = t; j < 3 * KB; j += 256)
        if (hist[j]) atomicAdd(&bCnt[j], hist[j]);
}

__global__ void bucket_scan(const int* __restrict__ bCnt, int* __restrict__ bBase,
                            int* __restrict__ gCursor, int* __restrict__ rs) {
    __shared__ int hist[3 * KB];
    int t = threadIdx.x;
    if (t < 3 * KB) hist[t] = bCnt[t];
    __syncthreads();
    if (t < 3) {
        int run = 0;
        for (int b = 0; b < KB; ++b) {
            bBase[t * (KB + 1) + b] = run;
            gCursor[t * KB + b] = run;
            run += hist[t * KB + b];
        }
        bBase[t * (KB + 1) + KB] = run;           // == EE
        rs[(size_t)t * (NN + 1) + NN] = run;
    }
}

__global__ __launch_bounds__(256) void bucket_scatter(
    const int* __restrict__ s0, const int* __restrict__ d0,
    const int* __restrict__ s1, const int* __restrict__ d1,
    const int* __restrict__ s2, const int* __restrict__ d2,
    int* __restrict__ gCursor, unsigned int* __restrict__ binned) {
    __shared__ unsigned int recs[CH];
    __shared__ unsigned short rnk[CH];
    __shared__ unsigned char bkt[CH];
    __shared__ int cnt[KB];
    __shared__ int gpos[KB];
    int t = threadIdx.x;
    int type = blockIdx.x / BPT;
    int chunk = (blockIdx.x % BPT) * CH;
    const int* src = (type == 0) ? s0 : (type == 1) ? s1 : s2;
    const int* dst = (type == 0) ? d0 : (type == 1) ? d1 : d2;
    if (t < KB) cnt[t] = 0;
    __syncthreads();
#pragma unroll
    for (int k = 0; k < CH / 256; ++k) {
        int idx = k * 256 + t;
        int e = chunk + idx;
        if (e < EE) {
            int s = src[e], d = dst[e];
            int b = d >> GSH;
            recs[idx] = ((unsigned int)s << GSH) | (unsigned int)(d & (GSZ - 1));
            bkt[idx] = (unsigned char)b;
            rnk[idx] = (unsigned short)atomicAdd(&cnt[b], 1);
        } else {
            bkt[idx] = 0xFF;
        }
    }
    __syncthreads();
    if (t < KB) {
        int c = cnt[t];
        gpos[t] = (c > 0) ? atomicAdd(&gCursor[type * KB + t], c) : 0;
    }
    __syncthreads();
    unsigned int* bout = binned + (size_t)type * EE;
#pragma unroll
    for (int k = 0; k < CH / 256; ++k) {
        int idx = k * 256 + t;
        unsigned char b = bkt[idx];
        if (b != 0xFF) bout[gpos[b] + rnk[idx]] = recs[idx];
    }
}

__global__ __launch_bounds__(256) void bucket_sort(
    const unsigned int* __restrict__ binned, const int* __restrict__ bBase,
    int* __restrict__ rs, int* __restrict__ sorted) {
    __shared__ int cnt[GSZ];
    __shared__ int tsum[256];
    int t = threadIdx.x;
    int type = blockIdx.x / KB;
    int b = blockIdx.x % KB;
    int nodeBase = b * GSZ;
    int eb = bBase[type * (KB + 1) + b];
    int en = bBase[type * (KB + 1) + b + 1];
    int n = en - eb;
    const unsigned int* bin = binned + (size_t)type * EE + eb;
#pragma unroll
    for (int k = 0; k < GSZ / 256; ++k) cnt[k * 256 + t] = 0;
    __syncthreads();
    for (int i = t; i < n; i += 256) atomicAdd(&cnt[bin[i] & (GSZ - 1)], 1);
    __syncthreads();
    int v[4], s = 0;
#pragma unroll
    for (int k = 0; k < 4; ++k) { v[k] = cnt[t * 4 + k]; s += v[k]; }
    tsum[t] = s;
    __syncthreads();
    for (int off = 1; off < 256; off <<= 1) {
        int add = (t >= off) ? tsum[t - off] : 0;
        __syncthreads();
        tsum[t] += add;
        __syncthreads();
    }
    int run = tsum[t] - s;  // exclusive base for this thread's 4 nodes
    int offk[4];
#pragma unroll
    for (int k = 0; k < 4; ++k) { offk[k] = run; run += v[k]; }
    int* rsrow = rs + (size_t)type * (NN + 1) + nodeBase;
#pragma unroll
    for (int k = 0; k < 4; ++k) {
        int node = t * 4 + k;
        if (nodeBase + node < NN) rsrow[node] = eb + offk[k];
    }
    __syncthreads();  // all cnt reads done before overwrite
#pragma unroll
    for (int k = 0; k < 4; ++k) cnt[t * 4 + k] = offk[k];
    __syncthreads();
    int* so = sorted + (size_t)type * EE + eb;
    for (int i = t; i < n; i += 256) {
        unsigned int r = bin[i];
        int dl = r & (GSZ - 1);
        int p = atomicAdd(&cnt[dl], 1);
        so[p] = (int)(r >> GSH);
    }
}

// Per-type P/Q node GEMM: M=100000, K=96, N=96 x 2 sections (y=0 -> P, y=1 -> Q)
__global__ __launch_bounds__(256) void node_gemm_kernel(const unsigned short* __restrict__ hb,
                                                        const unsigned short* __restrict__ BfN,
                                                        int t,
                                                        unsigned short* __restrict__ Pb,
                                                        unsigned short* __restrict__ Qb) {
    int wave = threadIdx.x >> 6;
    int lane = threadIdx.x & 63;
    int quad = lane >> 4, m = lane & 15;
    int blk = blockIdx.x * 4 + wave;
    if (blk >= NN / 16) return;
    int sec = t + 3 * blockIdx.y;                      // P section = t, Q section = t+3
    unsigned short* dst = blockIdx.y ? Qb : Pb;
    int r0 = blk * 16;
    f32x4 acc[6] = {};
    const unsigned short* arow = hb + (size_t)(r0 + m) * HH + quad * 8;
#pragma unroll
    for (int ks = 0; ks < 3; ++ks) {
        bf16x8 af = *(const bf16x8*)(arow + ks * 32);
#pragma unroll
        for (int c = 0; c < 6; ++c) {
            bf16x8 bfv = *(const bf16x8*)(BfN + (((sec * 3 + ks) * 6 + c) << 9) + lane * 8);
            acc[c] = __builtin_amdgcn_mfma_f32_16x16x32_bf16(af, bfv, acc[c], 0, 0, 0);
        }
    }
#pragma unroll
    for (int c = 0; c < 6; ++c)
#pragma unroll
        for (int r = 0; r < 4; ++r) {
            int row = r0 + quad * 4 + r;
            dst[(size_t)row * HH + c * 16 + m] = f2b(acc[c][r]);
        }
}

// Gather aggregation + fused finalize: one 32-lane group per dst node.
// Batched segment load + 4x unroll so the 12 P-row gathers issue independently.
// msg_t[d] = (sum_e w_e * P[src_e]) / (sum_e w_e) + Q[d] + cvec_t  (0 if no edges)
__global__ void aggregate_kernel(const int* __restrict__ rs, const int* __restrict__ sorted,
                                 const float* __restrict__ u, const float* __restrict__ vv,
                                 const unsigned short* __restrict__ P,
                                 const unsigned short* __restrict__ Q,
                                 const float* __restrict__ cvec_t, int is_attn,
                                 unsigned short* __restrict__ msgb_t) {
    int lane = threadIdx.x & 31;
    int node = (blockIdx.x * blockDim.x + threadIdx.x) >> 5;
    if (node >= NN) return;
    int beg = rs[node], end = rs[node + 1];
    float a0 = 0.f, a1 = 0.f, a2 = 0.f, den = 0.f;
    float vd = is_attn ? vv[node] : 0.f;
    for (int base = beg; base < end; base += 32) {
        int batch = end - base;
        if (batch > 32) batch = 32;
        // coalesced batch load of the segment (clamped for OOB lanes)
        int li = lane < batch ? lane : batch - 1;
        int myS = sorted[base + li];
#pragma unroll 1
        for (int j = 0; j < batch; j += 4) {
            int rem = batch - j;
            int s0 = __shfl(myS, j, 32);
            int s1 = __shfl(myS, rem > 1 ? j + 1 : j, 32);
            int s2 = __shfl(myS, rem > 2 ? j + 2 : j, 32);
            int s3 = __shfl(myS, rem > 3 ? j + 3 : j, 32);
            float w0, w1, w2, w3;
            if (is_attn) {
                float c0 = u[s0] + vd, c1 = u[s1] + vd, c2 = u[s2] + vd, c3 = u[s3] + vd;
                c0 = c0 > 0.f ? c0 : NEG * c0;
                c1 = c1 > 0.f ? c1 : NEG * c1;
                c2 = c2 > 0.f ? c2 : NEG * c2;
                c3 = c3 > 0.f ? c3 : NEG * c3;
                w0 = __expf(c0); w1 = __expf(c1); w2 = __expf(c2); w3 = __expf(c3);
            } else {
                w0 = w1 = w2 = w3 = 1.f;
            }
            if (rem < 4) { w3 = 0.f; if (rem < 3) { w2 = 0.f; if (rem < 2) w1 = 0.f; } }
            const unsigned short* p0 = P + (size_t)s0 * HH;
            const unsigned short* p1 = P + (size_t)s1 * HH;
            const unsigned short* p2 = P + (size_t)s2 * HH;
            const unsigned short* p3 = P + (size_t)s3 * HH;
            // independent gathers — compiler batches these before the waits
            float x00 = b2f(p0[lane]),      x01 = b2f(p0[lane + 32]), x02 = b2f(p0[lane + 64]);
            float x10 = b2f(p1[lane]),      x11 = b2f(p1[lane + 32]), x12 = b2f(p1[lane + 64]);
            float x20 = b2f(p2[lane]),      x21 = b2f(p2[lane + 32]), x22 = b2f(p2[lane + 64]);
            float x30 = b2f(p3[lane]),      x31 = b2f(p3[lane + 32]), x32 = b2f(p3[lane + 64]);
            den += w0 + w1 + w2 + w3;
            a0 += w0 * x00 + w1 * x10 + w2 * x20 + w3 * x30;
            a1 += w0 * x01 + w1 * x11 + w2 * x21 + w3 * x31;
            a2 += w0 * x02 + w1 * x12 + w2 * x22 + w3 * x32;
        }
    }
    float r0 = 0.f, r1 = 0.f, r2 = 0.f;
    if (den > 0.f) {
        float inv = 1.f / den;
        const unsigned short* qr = Q + (size_t)node * HH;
        r0 = a0 * inv + b2f(qr[lane]) + cvec_t[lane];
        r1 = a1 * inv + b2f(qr[lane + 32]) + cvec_t[lane + 32];
        r2 = a2 * inv + b2f(qr[lane + 64]) + cvec_t[lane + 64];
    }
    unsigned short* mr = msgb_t + (size_t)node * 288;
    mr[lane] = f2b(r0);
    mr[lane + 32] = f2b(r1);
    mr[lane + 64] = f2b(r2);
}

// out = relu([h | msg] @ Wu + bu): M=100000, K=384, N=96
__global__ __launch_bounds__(256) void update_gemm_kernel(const unsigned short* __restrict__ hb,
                                                          const unsigned short* __restrict__ msgb,
                                                          const unsigned short* __restrict__ BfU,
                                                          const float* __restrict__ bu,
                                                          float* __restrict__ out) {
    int wave = threadIdx.x >> 6;
    int lane = threadIdx.x & 63;
    int quad = lane >> 4, m = lane & 15;
    int blk = blockIdx.x * 4 + wave;
    if (blk >= NN / 16) return;
    int r0 = blk * 16;
    f32x4 acc[6] = {};
#pragma unroll
    for (int ks = 0; ks < 12; ++ks) {
        const unsigned short* ap =
            (ks < 3) ? hb + (size_t)(r0 + m) * HH + ks * 32 + quad * 8
                     : msgb + (size_t)(r0 + m) * 288 + (ks - 3) * 32 + quad * 8;
        bf16x8 af = *(const bf16x8*)ap;
#pragma unroll
        for (int c = 0; c < 6; ++c) {
            bf16x8 bfv = *(const bf16x8*)(BfU + ((ks * 6 + c) << 9) + lane * 8);
            acc[c] = __builtin_amdgcn_mfma_f32_16x16x32_bf16(af, bfv, acc[c], 0, 0, 0);
        }
    }
#pragma unroll
    for (int c = 0; c < 6; ++c) {
        float b = bu[c * 16 + m];
#pragma unroll
        for (int r = 0; r < 4; ++r) {
            int row = r0 + quad * 4 + r;
            float v2 = acc[c][r] + b;
            out[(size_t)row * HH + c * 16 + m] = v2 > 0.f ? v2 : 0.f;
        }
    }
}

extern "C" void kernel_launch(void* const* d_in, const int* in_sizes, int n_in,
                              void* d_out, int out_size, void* d_ws, size_t ws_size,
                              hipStream_t stream) {
    (void)in_sizes; (void)n_in; (void)out_size;
    const float* h   = (const float*)d_in[0];
    const int* srcs[3] = {(const int*)d_in[1], (const int*)d_in[3], (const int*)d_in[5]};
    const int* dsts[3] = {(const int*)d_in[2], (const int*)d_in[4], (const int*)d_in[6]};
    const float* Wm0 = (const float*)d_in[7];
    const float* bm0 = (const float*)d_in[8];
    const float* ef0 = (const float*)d_in[9];
    const float* Wm1 = (const float*)d_in[10];
    const float* bm1 = (const float*)d_in[11];
    const float* ef1 = (const float*)d_in[12];
    const float* Wm2 = (const float*)d_in[13];
    const float* bm2 = (const float*)d_in[14];
    const float* ef2 = (const float*)d_in[15];
    const float* Wn0 = (const float*)d_in[16];
    const float* Wa0 = (const float*)d_in[17];
    const float* Wn1 = (const float*)d_in[18];
    const float* Wa1 = (const float*)d_in[19];
    const float* Wu  = (const float*)d_in[20];
    const float* bu  = (const float*)d_in[21];
    float* out = (float*)d_out;

    // Workspace layout (total ~130.2 MB; run 2 proved ws_size >= 155.8 MB)
    const size_t NEED = 130191104;
    if (ws_size < NEED) return;  // fail validation cleanly instead of faulting
    char* w = (char*)d_ws;
    unsigned short* msgb    = (unsigned short*)(w + 0);            // N*288 bf16
    unsigned short* hb      = (unsigned short*)(w + 57600000);     // N*96 bf16
    unsigned short* Pb      = (unsigned short*)(w + 76800000);     // N*96 bf16 (per type)
    unsigned short* Qb      = (unsigned short*)(w + 96000000);     // N*96 bf16 (per type)
    float*          uv      = (float*)(w + 115200000);             // 4*N f32
    float*          cvec    = (float*)(w + 116800000);             // 288 f32
    float*          wvec    = (float*)(w + 116801280);             // 384 f32
    unsigned short* BfN     = (unsigned short*)(w + 116802816);    // 55296 bf16
    unsigned short* BfU     = (unsigned short*)(w + 116913408);    // 36864 bf16
    int*            bBase   = (int*)(w + 116987136);               // 3*(KB+1) int
    int*            gCursor = (int*)(w + 116988416);               // 3*KB int
    int*            bCnt    = (int*)(w + 116989696);               // 3*KB int
    int*            rs      = (int*)(w + 116990976);               // 3*(N+1) int
    int*            sorted  = (int*)(w + 118191104);               // 3*E int
    unsigned int*   binned  = (unsigned int*)(w + 124191104);      // 3*E u32

    prep_kernel<<<128, 256, 0, stream>>>(Wm0, bm0, ef0, Wm1, bm1, ef1, Wm2, bm2, ef2,
                                         Wn0, Wa0, Wn1, Wa1, Wu, cvec, wvec, BfN, BfU);
    cast_uv_kernel<<<12500, 256, 0, stream>>>(h, wvec, hb, uv);

    // CSR build for all 3 edge types (bucketed two-level sort)
    zero_kernel<<<1, 256, 0, stream>>>((float4*)bCnt, 80);
    bucket_hist<<<512, 256, 0, stream>>>(dsts[0], dsts[1], dsts[2], bCnt);
    bucket_scan<<<1, 384, 0, stream>>>(bCnt, bBase, gCursor, rs);
    bucket_scatter<<<3 * BPT, 256, 0, stream>>>(srcs[0], dsts[0], srcs[1], dsts[1],
                                                srcs[2], dsts[2], gCursor, binned);
    bucket_sort<<<3 * KB, 256, 0, stream>>>(binned, bBase, rs, sorted);

    for (int t = 0; t < 3; ++t) {
        node_gemm_kernel<<<dim3(1563, 2), 256, 0, stream>>>(hb, BfN, t, Pb, Qb);
        aggregate_kernel<<<12500, 256, 0, stream>>>(rs + t * (NN + 1), sorted + t * EE,
                                                    uv + 2 * t * NN, uv + (2 * t + 1) * NN,
                                                    Pb, Qb, cvec + t * 96, (t < 2) ? 1 : 0,
                                                    msgb + t * 96);
    }

    update_gemm_kernel<<<1563, 256, 0, stream>>>(hb, msgb, BfU, bu, out);
}

// Round 6
// 346.928 us; speedup vs baseline: 2.4296x; 1.0471x over previous
//
#include <hip/hip_runtime.h>
#include <hip/hip_bf16.h>
#include <cstdint>

// Problem constants (fixed by reference)
#define NN 100000
#define HH 96
#define AD 32
#define DE 16
#define EE 500000
#define NEG 0.01f

// Bucketing: 98 buckets of 1024 nodes per edge type
#define GSH 10
#define GSZ 1024
#define KB 98
#define CH 4096
#define BPT 123   // ceil(EE/CH)

typedef __bf16 bf16x8 __attribute__((ext_vector_type(8)));
typedef float  f32x4  __attribute__((ext_vector_type(4)));

__device__ __forceinline__ unsigned short f2b(float x) {
    union { float f; unsigned int u; } v; v.f = x;
    unsigned int r = v.u + 0x7fffu + ((v.u >> 16) & 1u);  // RNE
    return (unsigned short)(r >> 16);
}
__device__ __forceinline__ float b2f(unsigned short h) {
    union { unsigned int u; float f; } v; v.u = ((unsigned int)h) << 16;
    return v.f;
}

// ---------------------------------------------------------------------------
// prep: cvec[3][96], wvec[4][96], B-fragment-swizzled bf16 weights.
// BfN: 6 sections (P0,P1,P2,Q0,Q1,Q2) x 3 ksteps x 6 colblocks x 64 lanes x 8
// BfU: 12 ksteps x 6 colblocks x 64 lanes x 8   (Wu 384x96)
// B-frag for mfma_f32_16x16x32_bf16: lane = ((k%32)/8)*16 + (n%16), j = k%8
// ---------------------------------------------------------------------------
__global__ void prep_kernel(const float* Wm0, const float* bm0, const float* ef0,
                            const float* Wm1, const float* bm1, const float* ef1,
                            const float* Wm2, const float* bm2, const float* ef2,
                            const float* Wn0, const float* Wa0,
                            const float* Wn1, const float* Wa1,
                            const float* Wu,
                            float* cvec, float* wvec,
                            unsigned short* BfN, unsigned short* BfU) {
    const float* Wm[3] = {Wm0, Wm1, Wm2};
    const float* bm[3] = {bm0, bm1, bm2};
    const float* ef[3] = {ef0, ef1, ef2};
    const int total = 288 + 384 + 55296 + 36864;
    for (int i = blockIdx.x * blockDim.x + threadIdx.x; i < total;
         i += gridDim.x * blockDim.x) {
        if (i < 288) {
            int t = i / 96, j = i % 96;
            float s = bm[t][j];
            for (int k = 0; k < DE; ++k) s += ef[t][k] * Wm[t][(2 * HH + k) * HH + j];
            cvec[i] = s;
        } else if (i < 288 + 384) {
            int ii = i - 288;
            int kind = ii / 96, k = ii % 96;
            const float* Wn = (kind < 2) ? Wn0 : Wn1;
            const float* Wa = (kind < 2) ? Wa0 : Wa1;
            int off = (kind & 1) ? AD : 0;
            float s = 0.f;
            for (int a = 0; a < AD; ++a) s += Wn[k * AD + a] * Wa[off + a];
            wvec[ii] = s;
        } else if (i < 288 + 384 + 55296) {
            int ii = i - 672;
            int sec = ii / 9216; int rem = ii % 9216;
            int ksc = rem / 512; int lj = rem % 512;
            int ks = ksc / 6, c = ksc % 6;
            int lane = lj / 8, jj = lj % 8;
            int quad = lane / 16, m = lane % 16;
            int k = ks * 32 + quad * 8 + jj;
            int n = c * 16 + m;
            int mt = (sec < 3) ? sec : sec - 3;
            int rowoff = (sec < 3) ? 0 : HH;
            BfN[ii] = f2b(Wm[mt][(rowoff + k) * HH + n]);
        } else {
            int ii = i - (672 + 55296);
            int ksc = ii / 512; int lj = ii % 512;
            int ks = ksc / 6, c = ksc % 6;
            int lane = lj / 8, jj = lj % 8;
            int quad = lane / 16, m = lane % 16;
            int k = ks * 32 + quad * 8 + jj;
            int n = c * 16 + m;
            BfU[ii] = f2b(Wu[k * HH + n]);
        }
    }
}

// Fused: bf16 cast of h + u/v attention pre-dots. One 32-lane group per node.
__global__ void cast_uv_kernel(const float* __restrict__ h, const float* __restrict__ wvec,
                               unsigned short* __restrict__ hb, float* __restrict__ uv) {
    int lane = threadIdx.x & 31;
    int node = (blockIdx.x * blockDim.x + threadIdx.x) >> 5;
    if (node >= NN) return;
    float h0 = h[node * HH + lane];
    float h1 = h[node * HH + 32 + lane];
    float h2 = h[node * HH + 64 + lane];
    hb[node * HH + lane] = f2b(h0);
    hb[node * HH + 32 + lane] = f2b(h1);
    hb[node * HH + 64 + lane] = f2b(h2);
    float acc[4];
#pragma unroll
    for (int q = 0; q < 4; ++q)
        acc[q] = h0 * wvec[q * 96 + lane] + h1 * wvec[q * 96 + 32 + lane] +
                 h2 * wvec[q * 96 + 64 + lane];
#pragma unroll
    for (int d = 16; d >= 1; d >>= 1)
#pragma unroll
        for (int q = 0; q < 4; ++q) acc[q] += __shfl_down(acc[q], d, 32);
    if (lane == 0) {
#pragma unroll
        for (int q = 0; q < 4; ++q) uv[q * NN + node] = acc[q];
    }
}

__global__ void zero_kernel(float4* __restrict__ p, int n4) {
    for (int i = blockIdx.x * blockDim.x + threadIdx.x; i < n4;
         i += gridDim.x * blockDim.x)
        p[i] = make_float4(0.f, 0.f, 0.f, 0.f);
}

// ---------------------------------------------------------------------------
// Two-level CSR build: bucket hist -> scan -> LDS-ranked scatter (line-dense
// runs) -> per-bucket counting sort confined to one CU's L2 span.
// ---------------------------------------------------------------------------
__global__ void bucket_hist(const int* __restrict__ d0, const int* __restrict__ d1,
                            const int* __restrict__ d2, int* __restrict__ bCnt) {
    __shared__ int hist[3 * KB];
    int t = threadIdx.x;
    for (int j = t; j < 3 * KB; j += 256) hist[j] = 0;
    __syncthreads();
    const int total = 3 * EE;
    for (int i = blockIdx.x * blockDim.x + t; i < total; i += gridDim.x * blockDim.x) {
        int ty = i / EE, e = i - ty * EE;
        const int* d = (ty == 0) ? d0 : (ty == 1) ? d1 : d2;
        atomicAdd(&hist[ty * KB + (d[e] >> GSH)], 1);
    }
    __syncthreads();
    for (int j = t; j < 3 * KB; j += 256)
        if (hist[j]) atomicAdd(&bCnt[j], hist[j]);
}

__global__ void bucket_scan(const int* __restrict__ bCnt, int* __restrict__ bBase,
                            int* __restrict__ gCursor, int* __restrict__ rs) {
    __shared__ int hist[3 * KB];
    int t = threadIdx.x;
    if (t < 3 * KB) hist[t] = bCnt[t];
    __syncthreads();
    if (t < 3) {
        int run = 0;
        for (int b = 0; b < KB; ++b) {
            bBase[t * (KB + 1) + b] = run;
            gCursor[t * KB + b] = run;
            run += hist[t * KB + b];
        }
        bBase[t * (KB + 1) + KB] = run;           // == EE
        rs[(size_t)t * (NN + 1) + NN] = run;
    }
}

__global__ __launch_bounds__(256) void bucket_scatter(
    const int* __restrict__ s0, const int* __restrict__ d0,
    const int* __restrict__ s1, const int* __restrict__ d1,
    const int* __restrict__ s2, const int* __restrict__ d2,
    int* __restrict__ gCursor, unsigned int* __restrict__ binned) {
    __shared__ unsigned int recs[CH];
    __shared__ unsigned short rnk[CH];
    __shared__ unsigned char bkt[CH];
    __shared__ int cnt[KB];
    __shared__ int gpos[KB];
    int t = threadIdx.x;
    int type = blockIdx.x / BPT;
    int chunk = (blockIdx.x % BPT) * CH;
    const int* src = (type == 0) ? s0 : (type == 1) ? s1 : s2;
    const int* dst = (type == 0) ? d0 : (type == 1) ? d1 : d2;
    if (t < KB) cnt[t] = 0;
    __syncthreads();
#pragma unroll
    for (int k = 0; k < CH / 256; ++k) {
        int idx = k * 256 + t;
        int e = chunk + idx;
        if (e < EE) {
            int s = src[e], d = dst[e];
            int b = d >> GSH;
            recs[idx] = ((unsigned int)s << GSH) | (unsigned int)(d & (GSZ - 1));
            bkt[idx] = (unsigned char)b;
            rnk[idx] = (unsigned short)atomicAdd(&cnt[b], 1);
        } else {
            bkt[idx] = 0xFF;
        }
    }
    __syncthreads();
    if (t < KB) {
        int c = cnt[t];
        gpos[t] = (c > 0) ? atomicAdd(&gCursor[type * KB + t], c) : 0;
    }
    __syncthreads();
    unsigned int* bout = binned + (size_t)type * EE;
#pragma unroll
    for (int k = 0; k < CH / 256; ++k) {
        int idx = k * 256 + t;
        unsigned char b = bkt[idx];
        if (b != 0xFF) bout[gpos[b] + rnk[idx]] = recs[idx];
    }
}

__global__ __launch_bounds__(256) void bucket_sort(
    const unsigned int* __restrict__ binned, const int* __restrict__ bBase,
    int* __restrict__ rs, int* __restrict__ sorted) {
    __shared__ int cnt[GSZ];
    __shared__ int tsum[256];
    int t = threadIdx.x;
    int type = blockIdx.x / KB;
    int b = blockIdx.x % KB;
    int nodeBase = b * GSZ;
    int eb = bBase[type * (KB + 1) + b];
    int en = bBase[type * (KB + 1) + b + 1];
    int n = en - eb;
    const unsigned int* bin = binned + (size_t)type * EE + eb;
#pragma unroll
    for (int k = 0; k < GSZ / 256; ++k) cnt[k * 256 + t] = 0;
    __syncthreads();
    for (int i = t; i < n; i += 256) atomicAdd(&cnt[bin[i] & (GSZ - 1)], 1);
    __syncthreads();
    int v[4], s = 0;
#pragma unroll
    for (int k = 0; k < 4; ++k) { v[k] = cnt[t * 4 + k]; s += v[k]; }
    tsum[t] = s;
    __syncthreads();
    for (int off = 1; off < 256; off <<= 1) {
        int add = (t >= off) ? tsum[t - off] : 0;
        __syncthreads();
        tsum[t] += add;
        __syncthreads();
    }
    int run = tsum[t] - s;  // exclusive base for this thread's 4 nodes
    int offk[4];
#pragma unroll
    for (int k = 0; k < 4; ++k) { offk[k] = run; run += v[k]; }
    int* rsrow = rs + (size_t)type * (NN + 1) + nodeBase;
#pragma unroll
    for (int k = 0; k < 4; ++k) {
        int node = t * 4 + k;
        if (nodeBase + node < NN) rsrow[node] = eb + offk[k];
    }
    __syncthreads();  // all cnt reads done before overwrite
#pragma unroll
    for (int k = 0; k < 4; ++k) cnt[t * 4 + k] = offk[k];
    __syncthreads();
    int* so = sorted + (size_t)type * EE + eb;
    for (int i = t; i < n; i += 256) {
        unsigned int r = bin[i];
        int dl = r & (GSZ - 1);
        int p = atomicAdd(&cnt[dl], 1);
        so[p] = (int)(r >> GSH);
    }
}

// All-type P/Q node GEMM in ONE launch: grid (1563, 6); y<3 -> P_y, y>=3 -> Q_{y-3}
__global__ __launch_bounds__(256) void node_gemm_kernel(const unsigned short* __restrict__ hb,
                                                        const unsigned short* __restrict__ BfN,
                                                        unsigned short* __restrict__ Pall,
                                                        unsigned short* __restrict__ Qall) {
    const size_t NH = (size_t)NN * HH;
    int wave = threadIdx.x >> 6;
    int lane = threadIdx.x & 63;
    int quad = lane >> 4, m = lane & 15;
    int blk = blockIdx.x * 4 + wave;
    if (blk >= NN / 16) return;
    int sec = blockIdx.y;
    unsigned short* dst = (sec < 3) ? (Pall + (size_t)sec * NH)
                                    : (Qall + (size_t)(sec - 3) * NH);
    int r0 = blk * 16;
    f32x4 acc[6] = {};
    const unsigned short* arow = hb + (size_t)(r0 + m) * HH + quad * 8;
#pragma unroll
    for (int ks = 0; ks < 3; ++ks) {
        bf16x8 af = *(const bf16x8*)(arow + ks * 32);
#pragma unroll
        for (int c = 0; c < 6; ++c) {
            bf16x8 bfv = *(const bf16x8*)(BfN + (((sec * 3 + ks) * 6 + c) << 9) + lane * 8);
            acc[c] = __builtin_amdgcn_mfma_f32_16x16x32_bf16(af, bfv, acc[c], 0, 0, 0);
        }
    }
#pragma unroll
    for (int c = 0; c < 6; ++c)
#pragma unroll
        for (int r = 0; r < 4; ++r) {
            int row = r0 + quad * 4 + r;
            dst[(size_t)row * HH + c * 16 + m] = f2b(acc[c][r]);
        }
}

// All-type gather aggregation + fused finalize in ONE launch: grid (12500, 3).
// One 32-lane group per dst node; 8-wide unrolled independent gathers.
// msg_t[d] = (sum_e w_e * P_t[src_e]) / (sum_e w_e) + Q_t[d] + cvec_t (0 if no edges)
__global__ void aggregate_kernel(const int* __restrict__ rsAll, const int* __restrict__ sortedAll,
                                 const float* __restrict__ uv,
                                 const unsigned short* __restrict__ Pall,
                                 const unsigned short* __restrict__ Qall,
                                 const float* __restrict__ cvec,
                                 unsigned short* __restrict__ msgb) {
    const size_t NH = (size_t)NN * HH;
    int lane = threadIdx.x & 31;
    int node = (blockIdx.x * blockDim.x + threadIdx.x) >> 5;
    if (node >= NN) return;
    int t = blockIdx.y;
    int is_attn = (t < 2);
    const int* rs = rsAll + (size_t)t * (NN + 1);
    const int* sorted = sortedAll + (size_t)t * EE;
    const float* u = uv + 2 * t * NN;
    const unsigned short* P = Pall + (size_t)t * NH;
    const unsigned short* Q = Qall + (size_t)t * NH;
    const float* cvec_t = cvec + t * 96;

    int beg = rs[node], end = rs[node + 1];
    float a0 = 0.f, a1 = 0.f, a2 = 0.f, den = 0.f;
    float vd = is_attn ? uv[(2 * t + 1) * NN + node] : 0.f;
    for (int base = beg; base < end; base += 32) {
        int batch = end - base;
        if (batch > 32) batch = 32;
        int li = lane < batch ? lane : batch - 1;
        int myS = sorted[base + li];
#pragma unroll 1
        for (int j = 0; j < batch; j += 8) {
            int rem = batch - j;
            int sI[8];
            float wv[8];
#pragma unroll
            for (int k = 0; k < 8; ++k) sI[k] = __shfl(myS, (k < rem ? j + k : j), 32);
            if (is_attn) {
#pragma unroll
                for (int k = 0; k < 8; ++k) {
                    float c = u[sI[k]] + vd;
                    c = c > 0.f ? c : NEG * c;
                    wv[k] = __expf(c);
                }
            } else {
#pragma unroll
                for (int k = 0; k < 8; ++k) wv[k] = 1.f;
            }
#pragma unroll
            for (int k = 0; k < 8; ++k) if (k >= rem) wv[k] = 0.f;
            float x0[8], x1[8], x2[8];
#pragma unroll
            for (int k = 0; k < 8; ++k) {
                const unsigned short* pr = P + (size_t)sI[k] * HH;
                x0[k] = b2f(pr[lane]);
                x1[k] = b2f(pr[lane + 32]);
                x2[k] = b2f(pr[lane + 64]);
            }
#pragma unroll
            for (int k = 0; k < 8; ++k) {
                den += wv[k];
                a0 += wv[k] * x0[k];
                a1 += wv[k] * x1[k];
                a2 += wv[k] * x2[k];
            }
        }
    }
    float r0 = 0.f, r1 = 0.f, r2 = 0.f;
    if (den > 0.f) {
        float inv = 1.f / den;
        const unsigned short* qr = Q + (size_t)node * HH;
        r0 = a0 * inv + b2f(qr[lane]) + cvec_t[lane];
        r1 = a1 * inv + b2f(qr[lane + 32]) + cvec_t[lane + 32];
        r2 = a2 * inv + b2f(qr[lane + 64]) + cvec_t[lane + 64];
    }
    unsigned short* mr = msgb + (size_t)node * 288 + t * 96;
    mr[lane] = f2b(r0);
    mr[lane + 32] = f2b(r1);
    mr[lane + 64] = f2b(r2);
}

// out = relu([h | msg] @ Wu + bu): M=100000, K=384, N=96
__global__ __launch_bounds__(256) void update_gemm_kernel(const unsigned short* __restrict__ hb,
                                                          const unsigned short* __restrict__ msgb,
                                                          const unsigned short* __restrict__ BfU,
                                                          const float* __restrict__ bu,
                                                          float* __restrict__ out) {
    int wave = threadIdx.x >> 6;
    int lane = threadIdx.x & 63;
    int quad = lane >> 4, m = lane & 15;
    int blk = blockIdx.x * 4 + wave;
    if (blk >= NN / 16) return;
    int r0 = blk * 16;
    f32x4 acc[6] = {};
#pragma unroll
    for (int ks = 0; ks < 12; ++ks) {
        const unsigned short* ap =
            (ks < 3) ? hb + (size_t)(r0 + m) * HH + ks * 32 + quad * 8
                     : msgb + (size_t)(r0 + m) * 288 + (ks - 3) * 32 + quad * 8;
        bf16x8 af = *(const bf16x8*)ap;
#pragma unroll
        for (int c = 0; c < 6; ++c) {
            bf16x8 bfv = *(const bf16x8*)(BfU + ((ks * 6 + c) << 9) + lane * 8);
            acc[c] = __builtin_amdgcn_mfma_f32_16x16x32_bf16(af, bfv, acc[c], 0, 0, 0);
        }
    }
#pragma unroll
    for (int c = 0; c < 6; ++c) {
        float b = bu[c * 16 + m];
#pragma unroll
        for (int r = 0; r < 4; ++r) {
            int row = r0 + quad * 4 + r;
            float v2 = acc[c][r] + b;
            out[(size_t)row * HH + c * 16 + m] = v2 > 0.f ? v2 : 0.f;
        }
    }
}

extern "C" void kernel_launch(void* const* d_in, const int* in_sizes, int n_in,
                              void* d_out, int out_size, void* d_ws, size_t ws_size,
                              hipStream_t stream) {
    (void)in_sizes; (void)n_in; (void)out_size;
    const float* h   = (const float*)d_in[0];
    const int* srcs[3] = {(const int*)d_in[1], (const int*)d_in[3], (const int*)d_in[5]};
    const int* dsts[3] = {(const int*)d_in[2], (const int*)d_in[4], (const int*)d_in[6]};
    const float* Wm0 = (const float*)d_in[7];
    const float* bm0 = (const float*)d_in[8];
    const float* ef0 = (const float*)d_in[9];
    const float* Wm1 = (const float*)d_in[10];
    const float* bm1 = (const float*)d_in[11];
    const float* ef1 = (const float*)d_in[12];
    const float* Wm2 = (const float*)d_in[13];
    const float* bm2 = (const float*)d_in[14];
    const float* ef2 = (const float*)d_in[15];
    const float* Wn0 = (const float*)d_in[16];
    const float* Wa0 = (const float*)d_in[17];
    const float* Wn1 = (const float*)d_in[18];
    const float* Wa1 = (const float*)d_in[19];
    const float* Wu  = (const float*)d_in[20];
    const float* bu  = (const float*)d_in[21];
    float* out = (float*)d_out;

    // Workspace layout (total ~207 MB; ws_size measured 256 MiB in round 5)
    const size_t NEED = 206991104;
    if (ws_size < NEED) return;  // fail validation cleanly instead of faulting
    char* w = (char*)d_ws;
    unsigned short* msgb    = (unsigned short*)(w + 0);            // N*288 bf16
    unsigned short* hb      = (unsigned short*)(w + 57600000);     // N*96 bf16
    unsigned short* Pall    = (unsigned short*)(w + 76800000);     // 3*N*96 bf16
    unsigned short* Qall    = (unsigned short*)(w + 134400000);    // 3*N*96 bf16
    float*          uv      = (float*)(w + 192000000);             // 4*N f32
    float*          cvec    = (float*)(w + 193600000);             // 288 f32
    float*          wvec    = (float*)(w + 193601280);             // 384 f32
    unsigned short* BfN     = (unsigned short*)(w + 193602816);    // 55296 bf16
    unsigned short* BfU     = (unsigned short*)(w + 193713408);    // 36864 bf16
    int*            bBase   = (int*)(w + 193787136);               // 3*(KB+1) int
    int*            gCursor = (int*)(w + 193788416);               // 3*KB int
    int*            bCnt    = (int*)(w + 193789696);               // 3*KB int
    int*            rs      = (int*)(w + 193790976);               // 3*(N+1) int
    int*            sorted  = (int*)(w + 194991104);               // 3*E int
    unsigned int*   binned  = (unsigned int*)(w + 200991104);      // 3*E u32

    prep_kernel<<<128, 256, 0, stream>>>(Wm0, bm0, ef0, Wm1, bm1, ef1, Wm2, bm2, ef2,
                                         Wn0, Wa0, Wn1, Wa1, Wu, cvec, wvec, BfN, BfU);
    cast_uv_kernel<<<12500, 256, 0, stream>>>(h, wvec, hb, uv);

    // CSR build for all 3 edge types (bucketed two-level sort)
    zero_kernel<<<1, 256, 0, stream>>>((float4*)bCnt, 80);
    bucket_hist<<<512, 256, 0, stream>>>(dsts[0], dsts[1], dsts[2], bCnt);
    bucket_scan<<<1, 384, 0, stream>>>(bCnt, bBase, gCursor, rs);
    bucket_scatter<<<3 * BPT, 256, 0, stream>>>(srcs[0], dsts[0], srcs[1], dsts[1],
                                                srcs[2], dsts[2], gCursor, binned);
    bucket_sort<<<3 * KB, 256, 0, stream>>>(binned, bBase, rs, sorted);

    node_gemm_kernel<<<dim3(1563, 6), 256, 0, stream>>>(hb, BfN, Pall, Qall);
    aggregate_kernel<<<dim3(12500, 3), 256, 0, stream>>>(rs, sorted, uv, Pall, Qall,
                                                         cvec, msgb);
    update_gemm_kernel<<<1563, 256, 0, stream>>>(hb, msgb, BfU, bu, out);
}

// Round 7
// 331.465 us; speedup vs baseline: 2.5430x; 1.0467x over previous
//
#include <hip/hip_runtime.h>
#include <hip/hip_bf16.h>
#include <cstdint>

// Problem constants (fixed by reference)
#define NN 100000
#define HH 96
#define AD 32
#define DE 16
#define EE 500000
#define NEG 0.01f

// Bucketing: 98 buckets of 1024 nodes per edge type
#define GSH 10
#define GSZ 1024
#define KB 98
#define CH 4096
#define BPT 123   // ceil(EE/CH)

typedef __bf16 bf16x8 __attribute__((ext_vector_type(8)));
typedef float  f32x4  __attribute__((ext_vector_type(4)));

__device__ __forceinline__ unsigned short f2b(float x) {
    union { float f; unsigned int u; } v; v.f = x;
    unsigned int r = v.u + 0x7fffu + ((v.u >> 16) & 1u);  // RNE
    return (unsigned short)(r >> 16);
}
__device__ __forceinline__ float b2f(unsigned short h) {
    union { unsigned int u; float f; } v; v.u = ((unsigned int)h) << 16;
    return v.f;
}

// ---------------------------------------------------------------------------
// prep: cvec[3][96], wvec[4][96], B-fragment-swizzled bf16 weights.
// BfN: 6 sections (S0,S1,S2,D0,D1,D2) x 3 ksteps x 6 colblocks x 64 lanes x 8
//   (S = Wm rows 0..95 [src part], D = Wm rows 96..191 [dst part])
// BfU: 12 ksteps x 6 colblocks x 64 lanes x 8   (Wu 384x96)
// B-frag for mfma_f32_16x16x32_bf16: lane = ((k%32)/8)*16 + (n%16), j = k%8
// ---------------------------------------------------------------------------
__global__ void prep_kernel(const float* Wm0, const float* bm0, const float* ef0,
                            const float* Wm1, const float* bm1, const float* ef1,
                            const float* Wm2, const float* bm2, const float* ef2,
                            const float* Wn0, const float* Wa0,
                            const float* Wn1, const float* Wa1,
                            const float* Wu,
                            float* cvec, float* wvec,
                            unsigned short* BfN, unsigned short* BfU) {
    const float* Wm[3] = {Wm0, Wm1, Wm2};
    const float* bm[3] = {bm0, bm1, bm2};
    const float* ef[3] = {ef0, ef1, ef2};
    const int total = 288 + 384 + 55296 + 36864;
    for (int i = blockIdx.x * blockDim.x + threadIdx.x; i < total;
         i += gridDim.x * blockDim.x) {
        if (i < 288) {
            int t = i / 96, j = i % 96;
            float s = bm[t][j];
            for (int k = 0; k < DE; ++k) s += ef[t][k] * Wm[t][(2 * HH + k) * HH + j];
            cvec[i] = s;
        } else if (i < 288 + 384) {
            int ii = i - 288;
            int kind = ii / 96, k = ii % 96;
            const float* Wn = (kind < 2) ? Wn0 : Wn1;
            const float* Wa = (kind < 2) ? Wa0 : Wa1;
            int off = (kind & 1) ? AD : 0;
            float s = 0.f;
            for (int a = 0; a < AD; ++a) s += Wn[k * AD + a] * Wa[off + a];
            wvec[ii] = s;
        } else if (i < 288 + 384 + 55296) {
            int ii = i - 672;
            int sec = ii / 9216; int rem = ii % 9216;
            int ksc = rem / 512; int lj = rem % 512;
            int ks = ksc / 6, c = ksc % 6;
            int lane = lj / 8, jj = lj % 8;
            int quad = lane / 16, m = lane % 16;
            int k = ks * 32 + quad * 8 + jj;
            int n = c * 16 + m;
            int mt = (sec < 3) ? sec : sec - 3;
            int rowoff = (sec < 3) ? 0 : HH;
            BfN[ii] = f2b(Wm[mt][(rowoff + k) * HH + n]);
        } else {
            int ii = i - (672 + 55296);
            int ksc = ii / 512; int lj = ii % 512;
            int ks = ksc / 6, c = ksc % 6;
            int lane = lj / 8, jj = lj % 8;
            int quad = lane / 16, m = lane % 16;
            int k = ks * 32 + quad * 8 + jj;
            int n = c * 16 + m;
            BfU[ii] = f2b(Wu[k * HH + n]);
        }
    }
}

// Fused: bf16 cast of h + u/v attention pre-dots. One 32-lane group per node.
__global__ void cast_uv_kernel(const float* __restrict__ h, const float* __restrict__ wvec,
                               unsigned short* __restrict__ hb, float* __restrict__ uv) {
    int lane = threadIdx.x & 31;
    int node = (blockIdx.x * blockDim.x + threadIdx.x) >> 5;
    if (node >= NN) return;
    float h0 = h[node * HH + lane];
    float h1 = h[node * HH + 32 + lane];
    float h2 = h[node * HH + 64 + lane];
    hb[node * HH + lane] = f2b(h0);
    hb[node * HH + 32 + lane] = f2b(h1);
    hb[node * HH + 64 + lane] = f2b(h2);
    float acc[4];
#pragma unroll
    for (int q = 0; q < 4; ++q)
        acc[q] = h0 * wvec[q * 96 + lane] + h1 * wvec[q * 96 + 32 + lane] +
                 h2 * wvec[q * 96 + 64 + lane];
#pragma unroll
    for (int d = 16; d >= 1; d >>= 1)
#pragma unroll
        for (int q = 0; q < 4; ++q) acc[q] += __shfl_down(acc[q], d, 32);
    if (lane == 0) {
#pragma unroll
        for (int q = 0; q < 4; ++q) uv[q * NN + node] = acc[q];
    }
}

__global__ void zero_kernel(float4* __restrict__ p, int n4) {
    for (int i = blockIdx.x * blockDim.x + threadIdx.x; i < n4;
         i += gridDim.x * blockDim.x)
        p[i] = make_float4(0.f, 0.f, 0.f, 0.f);
}

// ---------------------------------------------------------------------------
// Two-level CSR build: bucket hist -> scan -> LDS-ranked scatter (line-dense
// runs) -> per-bucket counting sort confined to one CU's L2 span.
// ---------------------------------------------------------------------------
__global__ void bucket_hist(const int* __restrict__ d0, const int* __restrict__ d1,
                            const int* __restrict__ d2, int* __restrict__ bCnt) {
    __shared__ int hist[3 * KB];
    int t = threadIdx.x;
    for (int j = t; j < 3 * KB; j += 256) hist[j] = 0;
    __syncthreads();
    const int total = 3 * EE;
    for (int i = blockIdx.x * blockDim.x + t; i < total; i += gridDim.x * blockDim.x) {
        int ty = i / EE, e = i - ty * EE;
        const int* d = (ty == 0) ? d0 : (ty == 1) ? d1 : d2;
        atomicAdd(&hist[ty * KB + (d[e] >> GSH)], 1);
    }
    __syncthreads();
    for (int j = t; j < 3 * KB; j += 256)
        if (hist[j]) atomicAdd(&bCnt[j], hist[j]);
}

__global__ void bucket_scan(const int* __restrict__ bCnt, int* __restrict__ bBase,
                            int* __restrict__ gCursor, int* __restrict__ rs) {
    __shared__ int hist[3 * KB];
    int t = threadIdx.x;
    if (t < 3 * KB) hist[t] = bCnt[t];
    __syncthreads();
    if (t < 3) {
        int run = 0;
        for (int b = 0; b < KB; ++b) {
            bBase[t * (KB + 1) + b] = run;
            gCursor[t * KB + b] = run;
            run += hist[t * KB + b];
        }
        bBase[t * (KB + 1) + KB] = run;           // == EE
        rs[(size_t)t * (NN + 1) + NN] = run;
    }
}

__global__ __launch_bounds__(256) void bucket_scatter(
    const int* __restrict__ s0, const int* __restrict__ d0,
    const int* __restrict__ s1, const int* __restrict__ d1,
    const int* __restrict__ s2, const int* __restrict__ d2,
    int* __restrict__ gCursor, unsigned int* __restrict__ binned) {
    __shared__ unsigned int recs[CH];
    __shared__ unsigned short rnk[CH];
    __shared__ unsigned char bkt[CH];
    __shared__ int cnt[KB];
    __shared__ int gpos[KB];
    int t = threadIdx.x;
    int type = blockIdx.x / BPT;
    int chunk = (blockIdx.x % BPT) * CH;
    const int* src = (type == 0) ? s0 : (type == 1) ? s1 : s2;
    const int* dst = (type == 0) ? d0 : (type == 1) ? d1 : d2;
    if (t < KB) cnt[t] = 0;
    __syncthreads();
#pragma unroll
    for (int k = 0; k < CH / 256; ++k) {
        int idx = k * 256 + t;
        int e = chunk + idx;
        if (e < EE) {
            int s = src[e], d = dst[e];
            int b = d >> GSH;
            recs[idx] = ((unsigned int)s << GSH) | (unsigned int)(d & (GSZ - 1));
            bkt[idx] = (unsigned char)b;
            rnk[idx] = (unsigned short)atomicAdd(&cnt[b], 1);
        } else {
            bkt[idx] = 0xFF;
        }
    }
    __syncthreads();
    if (t < KB) {
        int c = cnt[t];
        gpos[t] = (c > 0) ? atomicAdd(&gCursor[type * KB + t], c) : 0;
    }
    __syncthreads();
    unsigned int* bout = binned + (size_t)type * EE;
#pragma unroll
    for (int k = 0; k < CH / 256; ++k) {
        int idx = k * 256 + t;
        unsigned char b = bkt[idx];
        if (b != 0xFF) bout[gpos[b] + rnk[idx]] = recs[idx];
    }
}

__global__ __launch_bounds__(256) void bucket_sort(
    const unsigned int* __restrict__ binned, const int* __restrict__ bBase,
    int* __restrict__ rs, int* __restrict__ sorted) {
    __shared__ int cnt[GSZ];
    __shared__ int tsum[256];
    int t = threadIdx.x;
    int type = blockIdx.x / KB;
    int b = blockIdx.x % KB;
    int nodeBase = b * GSZ;
    int eb = bBase[type * (KB + 1) + b];
    int en = bBase[type * (KB + 1) + b + 1];
    int n = en - eb;
    const unsigned int* bin = binned + (size_t)type * EE + eb;
#pragma unroll
    for (int k = 0; k < GSZ / 256; ++k) cnt[k * 256 + t] = 0;
    __syncthreads();
    for (int i = t; i < n; i += 256) atomicAdd(&cnt[bin[i] & (GSZ - 1)], 1);
    __syncthreads();
    int v[4], s = 0;
#pragma unroll
    for (int k = 0; k < 4; ++k) { v[k] = cnt[t * 4 + k]; s += v[k]; }
    tsum[t] = s;
    __syncthreads();
    for (int off = 1; off < 256; off <<= 1) {
        int add = (t >= off) ? tsum[t - off] : 0;
        __syncthreads();
        tsum[t] += add;
        __syncthreads();
    }
    int run = tsum[t] - s;  // exclusive base for this thread's 4 nodes
    int offk[4];
#pragma unroll
    for (int k = 0; k < 4; ++k) { offk[k] = run; run += v[k]; }
    int* rsrow = rs + (size_t)type * (NN + 1) + nodeBase;
#pragma unroll
    for (int k = 0; k < 4; ++k) {
        int node = t * 4 + k;
        if (nodeBase + node < NN) rsrow[node] = eb + offk[k];
    }
    __syncthreads();  // all cnt reads done before overwrite
#pragma unroll
    for (int k = 0; k < 4; ++k) cnt[t * 4 + k] = offk[k];
    __syncthreads();
    int* so = sorted + (size_t)type * EE + eb;
    for (int i = t; i < n; i += 256) {
        unsigned int r = bin[i];
        int dl = r & (GSZ - 1);
        int p = atomicAdd(&cnt[dl], 1);
        so[p] = (int)(r >> GSH);
    }
}

// All-type h-space gather aggregation in ONE launch: grid (12500, 3).
// Linearity: (sum w*P[s])/W = ((sum w*h[s])/W) @ WmS, so gather h rows and
// defer the 96x96 GEMM to msg_gemm. hagg_t[d] = (sum w_e h[src_e])/sum w_e.
__global__ void aggregate_kernel(const int* __restrict__ rsAll, const int* __restrict__ sortedAll,
                                 const float* __restrict__ uv,
                                 const unsigned short* __restrict__ hb,
                                 unsigned short* __restrict__ hagg,
                                 float* __restrict__ den) {
    const size_t NH = (size_t)NN * HH;
    int lane = threadIdx.x & 31;
    int node = (blockIdx.x * blockDim.x + threadIdx.x) >> 5;
    if (node >= NN) return;
    int t = blockIdx.y;
    int is_attn = (t < 2);
    const int* rs = rsAll + (size_t)t * (NN + 1);
    const int* sorted = sortedAll + (size_t)t * EE;
    const float* u = uv + 2 * t * NN;

    int beg = rs[node], end = rs[node + 1];
    float a0 = 0.f, a1 = 0.f, a2 = 0.f, dn = 0.f;
    float vd = is_attn ? uv[(2 * t + 1) * NN + node] : 0.f;
    for (int base = beg; base < end; base += 32) {
        int batch = end - base;
        if (batch > 32) batch = 32;
        int li = lane < batch ? lane : batch - 1;
        int myS = sorted[base + li];
#pragma unroll 1
        for (int j = 0; j < batch; j += 8) {
            int rem = batch - j;
            int sI[8];
            float wv[8];
#pragma unroll
            for (int k = 0; k < 8; ++k) sI[k] = __shfl(myS, (k < rem ? j + k : j), 32);
            if (is_attn) {
#pragma unroll
                for (int k = 0; k < 8; ++k) {
                    float c = u[sI[k]] + vd;
                    c = c > 0.f ? c : NEG * c;
                    wv[k] = __expf(c);
                }
            } else {
#pragma unroll
                for (int k = 0; k < 8; ++k) wv[k] = 1.f;
            }
#pragma unroll
            for (int k = 0; k < 8; ++k) if (k >= rem) wv[k] = 0.f;
            float x0[8], x1[8], x2[8];
#pragma unroll
            for (int k = 0; k < 8; ++k) {
                const unsigned short* pr = hb + (size_t)sI[k] * HH;
                x0[k] = b2f(pr[lane]);
                x1[k] = b2f(pr[lane + 32]);
                x2[k] = b2f(pr[lane + 64]);
            }
#pragma unroll
            for (int k = 0; k < 8; ++k) {
                dn += wv[k];
                a0 += wv[k] * x0[k];
                a1 += wv[k] * x1[k];
                a2 += wv[k] * x2[k];
            }
        }
    }
    float r0 = 0.f, r1 = 0.f, r2 = 0.f;
    if (dn > 0.f) {
        float inv = 1.f / dn;
        r0 = a0 * inv; r1 = a1 * inv; r2 = a2 * inv;
    }
    unsigned short* mr = hagg + (size_t)t * NH + (size_t)node * HH;
    mr[lane] = f2b(r0);
    mr[lane + 32] = f2b(r1);
    mr[lane + 64] = f2b(r2);
    if (lane == 0) den[(size_t)t * NN + node] = dn;
}

// msg_t = z_t * ( hagg_t @ WmS_t + h @ WmD_t + c_t ), K=192 MFMA, grid (1563,3).
// z_t = (den_t > 0) per row. Writes bf16 into msgb[:, t*96:(t+1)*96].
__global__ __launch_bounds__(256) void msg_gemm_kernel(const unsigned short* __restrict__ hagg,
                                                       const unsigned short* __restrict__ hb,
                                                       const unsigned short* __restrict__ BfN,
                                                       const float* __restrict__ den,
                                                       const float* __restrict__ cvec,
                                                       unsigned short* __restrict__ msgb) {
    const size_t NH = (size_t)NN * HH;
    int wave = threadIdx.x >> 6;
    int lane = threadIdx.x & 63;
    int quad = lane >> 4, m = lane & 15;
    int blk = blockIdx.x * 4 + wave;
    if (blk >= NN / 16) return;
    int t = blockIdx.y;
    int r0 = blk * 16;
    const unsigned short* ha = hagg + (size_t)t * NH;
    f32x4 acc[6] = {};
#pragma unroll
    for (int ks = 0; ks < 6; ++ks) {
        const unsigned short* ap =
            (ks < 3) ? ha + (size_t)(r0 + m) * HH + ks * 32 + quad * 8
                     : hb + (size_t)(r0 + m) * HH + (ks - 3) * 32 + quad * 8;
        int sec = (ks < 3) ? t : t + 3;
        int kk = (ks < 3) ? ks : ks - 3;
        bf16x8 af = *(const bf16x8*)ap;
#pragma unroll
        for (int c = 0; c < 6; ++c) {
            bf16x8 bfv = *(const bf16x8*)(BfN + (((sec * 3 + kk) * 6 + c) << 9) + lane * 8);
            acc[c] = __builtin_amdgcn_mfma_f32_16x16x32_bf16(af, bfv, acc[c], 0, 0, 0);
        }
    }
    float dn[4];
#pragma unroll
    for (int r = 0; r < 4; ++r) dn[r] = den[(size_t)t * NN + r0 + quad * 4 + r];
#pragma unroll
    for (int c = 0; c < 6; ++c) {
        float cv = cvec[t * 96 + c * 16 + m];
#pragma unroll
        for (int r = 0; r < 4; ++r) {
            int row = r0 + quad * 4 + r;
            float val = (dn[r] > 0.f) ? (acc[c][r] + cv) : 0.f;
            msgb[(size_t)row * 288 + t * 96 + c * 16 + m] = f2b(val);
        }
    }
}

// out = relu([h | msg] @ Wu + bu): M=100000, K=384, N=96
__global__ __launch_bounds__(256) void update_gemm_kernel(const unsigned short* __restrict__ hb,
                                                          const unsigned short* __restrict__ msgb,
                                                          const unsigned short* __restrict__ BfU,
                                                          const float* __restrict__ bu,
                                                          float* __restrict__ out) {
    int wave = threadIdx.x >> 6;
    int lane = threadIdx.x & 63;
    int quad = lane >> 4, m = lane & 15;
    int blk = blockIdx.x * 4 + wave;
    if (blk >= NN / 16) return;
    int r0 = blk * 16;
    f32x4 acc[6] = {};
#pragma unroll
    for (int ks = 0; ks < 12; ++ks) {
        const unsigned short* ap =
            (ks < 3) ? hb + (size_t)(r0 + m) * HH + ks * 32 + quad * 8
                     : msgb + (size_t)(r0 + m) * 288 + (ks - 3) * 32 + quad * 8;
        bf16x8 af = *(const bf16x8*)ap;
#pragma unroll
        for (int c = 0; c < 6; ++c) {
            bf16x8 bfv = *(const bf16x8*)(BfU + ((ks * 6 + c) << 9) + lane * 8);
            acc[c] = __builtin_amdgcn_mfma_f32_16x16x32_bf16(af, bfv, acc[c], 0, 0, 0);
        }
    }
#pragma unroll
    for (int c = 0; c < 6; ++c) {
        float b = bu[c * 16 + m];
#pragma unroll
        for (int r = 0; r < 4; ++r) {
            int row = r0 + quad * 4 + r;
            float v2 = acc[c][r] + b;
            out[(size_t)row * HH + c * 16 + m] = v2 > 0.f ? v2 : 0.f;
        }
    }
}

extern "C" void kernel_launch(void* const* d_in, const int* in_sizes, int n_in,
                              void* d_out, int out_size, void* d_ws, size_t ws_size,
                              hipStream_t stream) {
    (void)in_sizes; (void)n_in; (void)out_size;
    const float* h   = (const float*)d_in[0];
    const int* srcs[3] = {(const int*)d_in[1], (const int*)d_in[3], (const int*)d_in[5]};
    const int* dsts[3] = {(const int*)d_in[2], (const int*)d_in[4], (const int*)d_in[6]};
    const float* Wm0 = (const float*)d_in[7];
    const float* bm0 = (const float*)d_in[8];
    const float* ef0 = (const float*)d_in[9];
    const float* Wm1 = (const float*)d_in[10];
    const float* bm1 = (const float*)d_in[11];
    const float* ef1 = (const float*)d_in[12];
    const float* Wm2 = (const float*)d_in[13];
    const float* bm2 = (const float*)d_in[14];
    const float* ef2 = (const float*)d_in[15];
    const float* Wn0 = (const float*)d_in[16];
    const float* Wa0 = (const float*)d_in[17];
    const float* Wn1 = (const float*)d_in[18];
    const float* Wa1 = (const float*)d_in[19];
    const float* Wu  = (const float*)d_in[20];
    const float* bu  = (const float*)d_in[21];
    float* out = (float*)d_out;

    // Workspace layout (total ~150.6 MB; ws_size measured 256 MiB in round 5)
    const size_t NEED = 150591104;
    if (ws_size < NEED) return;  // fail validation cleanly instead of faulting
    char* w = (char*)d_ws;
    unsigned short* msgb    = (unsigned short*)(w + 0);            // N*288 bf16
    unsigned short* hb      = (unsigned short*)(w + 57600000);     // N*96 bf16
    unsigned short* hagg    = (unsigned short*)(w + 76800000);     // 3*N*96 bf16
    float*          den     = (float*)(w + 134400000);             // 3*N f32
    float*          uv      = (float*)(w + 135600000);             // 4*N f32
    float*          cvec    = (float*)(w + 137200000);             // 288 f32
    float*          wvec    = (float*)(w + 137201280);             // 384 f32
    unsigned short* BfN     = (unsigned short*)(w + 137202816);    // 55296 bf16
    unsigned short* BfU     = (unsigned short*)(w + 137313408);    // 36864 bf16
    int*            bBase   = (int*)(w + 137387136);               // 3*(KB+1) int
    int*            gCursor = (int*)(w + 137388416);               // 3*KB int
    int*            bCnt    = (int*)(w + 137389696);               // 3*KB int
    int*            rs      = (int*)(w + 137390976);               // 3*(N+1) int
    int*            sorted  = (int*)(w + 138591104);               // 3*E int
    unsigned int*   binned  = (unsigned int*)(w + 144591104);      // 3*E u32

    prep_kernel<<<128, 256, 0, stream>>>(Wm0, bm0, ef0, Wm1, bm1, ef1, Wm2, bm2, ef2,
                                         Wn0, Wa0, Wn1, Wa1, Wu, cvec, wvec, BfN, BfU);
    cast_uv_kernel<<<12500, 256, 0, stream>>>(h, wvec, hb, uv);

    // CSR build for all 3 edge types (bucketed two-level sort)
    zero_kernel<<<1, 256, 0, stream>>>((float4*)bCnt, 80);
    bucket_hist<<<512, 256, 0, stream>>>(dsts[0], dsts[1], dsts[2], bCnt);
    bucket_scan<<<1, 384, 0, stream>>>(bCnt, bBase, gCursor, rs);
    bucket_scatter<<<3 * BPT, 256, 0, stream>>>(srcs[0], dsts[0], srcs[1], dsts[1],
                                                srcs[2], dsts[2], gCursor, binned);
    bucket_sort<<<3 * KB, 256, 0, stream>>>(binned, bBase, rs, sorted);

    aggregate_kernel<<<dim3(12500, 3), 256, 0, stream>>>(rs, sorted, uv, hb, hagg, den);
    msg_gemm_kernel<<<dim3(1563, 3), 256, 0, stream>>>(hagg, hb, BfN, den, cvec, msgb);
    update_gemm_kernel<<<1563, 256, 0, stream>>>(hb, msgb, BfU, bu, out);
}